// Round 1
// baseline (597.473 us; speedup 1.0000x reference)
//
#include <hip/hip_runtime.h>
#include <math.h>

// Problem dims (fixed)
//  N=2, T=2048, DM=1024, H=8, E=4, L=32, DK=DV=64
//  rec length per (n,e): L+T = 2080 rows of 64
//  uk[n,e,t,i,:] = rec[n,e,t+i+1,:]

// ---------------- K1: fused projection GEMM ----------------
// C[r][c] = sum_k X[r][k] * W[c][k], r in [0,4096), c in [0,1568)
// cols: [0,512)->K(h=c/64,d=c%64), [512,1024)->V, [1024,1536)->Q,
//       [1536,1568)->G = sigmoid(C + b_G[h*4+e]) stored (n,h,e,t)
__global__ __launch_bounds__(256) void gemm_proj(
    const float* __restrict__ X,
    const float* __restrict__ wK, const float* __restrict__ wV,
    const float* __restrict__ wQ, const float* __restrict__ wG,
    const float* __restrict__ bG,
    float* __restrict__ Kb, float* __restrict__ Vb, float* __restrict__ Qb,
    float* __restrict__ Gb)
{
  __shared__ float As[16][65];
  __shared__ float Bs[16][65];
  const int tid = threadIdx.x;
  const int tx = tid & 15;
  const int ty = tid >> 4;
  const int rb = blockIdx.x * 64;
  const int cb = blockIdx.y * 64;
  float acc[4][4] = {};
  for (int k0 = 0; k0 < 1024; k0 += 16) {
    const int idx = tid * 4;
    const int rl = idx >> 4;      // row/col local 0..63
    const int kk = idx & 15;      // 0,4,8,12
    float4 a4 = *(const float4*)(X + (size_t)(rb + rl) * 1024 + k0 + kk);
    As[kk+0][rl] = a4.x; As[kk+1][rl] = a4.y; As[kk+2][rl] = a4.z; As[kk+3][rl] = a4.w;
    const int c = cb + rl;
    float4 b4 = make_float4(0.f, 0.f, 0.f, 0.f);
    const float* src;
    if (c < 512)       src = wK + (size_t)c * 1024;
    else if (c < 1024) src = wV + (size_t)(c - 512) * 1024;
    else if (c < 1536) src = wQ + (size_t)(c - 1024) * 1024;
    else if (c < 1568) src = wG + (size_t)(c - 1536) * 1024;
    else               src = nullptr;
    if (src) b4 = *(const float4*)(src + k0 + kk);
    Bs[kk+0][rl] = b4.x; Bs[kk+1][rl] = b4.y; Bs[kk+2][rl] = b4.z; Bs[kk+3][rl] = b4.w;
    __syncthreads();
#pragma unroll
    for (int p = 0; p < 16; ++p) {
      float a[4], b[4];
#pragma unroll
      for (int i = 0; i < 4; ++i) a[i] = As[p][ty*4+i];
#pragma unroll
      for (int j = 0; j < 4; ++j) b[j] = Bs[p][tx*4+j];
#pragma unroll
      for (int i = 0; i < 4; ++i)
#pragma unroll
        for (int j = 0; j < 4; ++j)
          acc[i][j] = fmaf(a[i], b[j], acc[i][j]);
    }
    __syncthreads();
  }
#pragma unroll
  for (int i = 0; i < 4; ++i) {
    const int rr = rb + ty*4 + i;
    const int n = rr >> 11;
    const int t = rr & 2047;
#pragma unroll
    for (int j = 0; j < 4; ++j) {
      const int c = cb + tx*4 + j;
      const float v = acc[i][j];
      if (c < 512) {
        Kb[(size_t)((n*8 + (c >> 6)) * 2048 + t) * 64 + (c & 63)] = v;
      } else if (c < 1024) {
        const int cc = c - 512;
        Vb[(size_t)((n*8 + (cc >> 6)) * 2048 + t) * 64 + (cc & 63)] = v;
      } else if (c < 1536) {
        const int cc = c - 1024;
        Qb[(size_t)((n*8 + (cc >> 6)) * 2048 + t) * 64 + (cc & 63)] = v;
      } else if (c < 1568) {
        const int cc = c - 1536;  // h*4+e
        const float g = 1.0f / (1.0f + __expf(-(v + bG[cc])));
        Gb[(size_t)(n*32 + cc) * 2048 + t] = g;
      }
    }
  }
}

// ---------------- K2: gated combine + lag-32 linear scan ----------------
// rec[n,e,s,:]: s<32 -> init[e,s,:]; s=32+t -> (1-sum_h G[n,h,e,t])*rec[n,e,s-32,:]
//                                              + sum_h G[n,h,e,t]*K[n,h,t,:]
__global__ __launch_bounds__(256) void scan_kernel(
    const float* __restrict__ Gb,    // (n,h,e,t)
    const float* __restrict__ Kb,    // (n,h,t,d)
    const float* __restrict__ Vb,
    const float* __restrict__ initK, // (E,32,64)
    const float* __restrict__ initV,
    float* __restrict__ recK,        // (n,e,2080,64)
    float* __restrict__ recV)
{
  const int d  = threadIdx.x;                                // 0..63
  const int i  = blockIdx.y * blockDim.y + threadIdx.y;      // 0..31 (lane in chunk)
  const int ne = blockIdx.x;                                 // n*4+e
  const int n  = ne >> 2;
  const int e  = ne & 3;
  const bool isV = (blockIdx.z != 0);
  const float* src  = isV ? Vb : Kb;
  const float* init = isV ? initV : initK;
  float*       rec  = isV ? recV : recK;

  float y = init[(size_t)(e*32 + i) * 64 + d];
  rec[(size_t)(ne*2080 + i) * 64 + d] = y;
  const float* Gbase = Gb + (size_t)(n*32 + e) * 2048;       // + h*4*2048 + t
  for (int j = 0; j < 64; ++j) {
    const int t = j*32 + i;
    float gsum = 0.f, gx = 0.f;
#pragma unroll
    for (int h = 0; h < 8; ++h) {
      const float g = Gbase[(size_t)h * 8192 + t];
      gsum += g;
      gx = fmaf(g, src[(size_t)((n*8 + h) * 2048 + t) * 64 + d], gx);
    }
    y = fmaf(1.0f - gsum, y, gx);
    rec[(size_t)(ne*2080 + 32 + t) * 64 + d] = y;
  }
}

// ---------------- K3: sliding-window attention ----------------
// Block: 8 consecutive t (one wave each), all 8 heads, one n.
// LDS window: rows s = t0+1 .. t0+39 of rec_K/rec_V for all 4 e.
#define BT 8
#define RR (BT + 31)   // 39 rows
__global__ __launch_bounds__(512) void attn_kernel(
    const float* __restrict__ Qb,    // (n,h,t,64)
    const float* __restrict__ recK,  // (n,e,2080,64)
    const float* __restrict__ recV,
    float* __restrict__ Yb)          // (n*T, 512) ; col = h*64+d
{
  __shared__ float Ks[4 * RR * 65];
  __shared__ float Vs[4 * RR * 65];
  __shared__ float Qs[8][BT][64];
  const int tid  = threadIdx.x;
  const int lane = tid & 63;
  const int w    = tid >> 6;                 // wave = local t
  const int bx   = blockIdx.x;
  const int n    = bx / (2048 / BT);
  const int t0   = (bx % (2048 / BT)) * BT;

  for (int idx = tid; idx < 4 * RR * 64; idx += 512) {
    const int d = idx & 63;
    const int r = (idx >> 6) % RR;
    const int e = (idx >> 6) / RR;
    const int s = t0 + 1 + r;
    const size_t g = (size_t)((n*4 + e) * 2080 + s) * 64 + d;
    Ks[(e*RR + r) * 65 + d] = recK[g];
    Vs[(e*RR + r) * 65 + d] = recV[g];
  }
  for (int idx = tid; idx < 8 * BT * 64; idx += 512) {
    const int d  = idx & 63;
    const int tl = (idx >> 6) % BT;
    const int h  = (idx >> 6) / BT;
    Qs[h][tl][d] = Qb[(size_t)((n*8 + h) * 2048 + t0 + tl) * 64 + d];
  }
  __syncthreads();

  const int t  = t0 + w;
  const int e0 = lane >> 5, i0 = lane & 31;  // ei = lane
  const int r0 = (e0 * RR + (w + i0)) * 65;  // ei = lane      (e 0..1)
  const int r1 = ((e0 + 2) * RR + (w + i0)) * 65;  // ei = lane+64 (e 2..3)

  for (int h = 0; h < 8; ++h) {
    float s0 = 0.f, s1 = 0.f;
#pragma unroll 8
    for (int d = 0; d < 64; ++d) {
      const float q = Qs[h][w][d];
      s0 = fmaf(q, Ks[r0 + d], s0);
      s1 = fmaf(q, Ks[r1 + d], s1);
    }
    s0 *= 0.125f; s1 *= 0.125f;
    float m = fmaxf(s0, s1);
    for (int off = 32; off; off >>= 1) m = fmaxf(m, __shfl_xor(m, off));
    float p0 = __expf(s0 - m), p1 = __expf(s1 - m);
    float sum = p0 + p1;
    for (int off = 32; off; off >>= 1) sum += __shfl_xor(sum, off);
    const float inv = 1.0f / sum;
    p0 *= inv; p1 *= inv;
    // PV: lane = output d; broadcast attn from source lanes.
    float acc = 0.f;
#pragma unroll 8
    for (int ei = 0; ei < 64; ++ei) {
      const float a = __shfl(p0, ei);
      const int e = ei >> 5, ii = ei & 31;
      acc = fmaf(a, Vs[(e * RR + w + ii) * 65 + lane], acc);
    }
#pragma unroll 8
    for (int ei = 0; ei < 64; ++ei) {
      const float a = __shfl(p1, ei);
      const int e = 2 + (ei >> 5), ii = ei & 31;
      acc = fmaf(a, Vs[(e * RR + w + ii) * 65 + lane], acc);
    }
    Yb[(size_t)(n*2048 + t) * 512 + h*64 + lane] = acc;
  }
}

// ---------------- K4: output GEMM ----------------
// out[r][c] = sum_k Yb[r][k] * wO[k][c], (4096 x 512) @ (512 x 1024)
__global__ __launch_bounds__(256) void gemm_out(
    const float* __restrict__ Yb,
    const float* __restrict__ wO,
    float* __restrict__ out)
{
  __shared__ float As[16][65];
  __shared__ float Bs[16][65];
  const int tid = threadIdx.x;
  const int tx = tid & 15;
  const int ty = tid >> 4;
  const int rb = blockIdx.x * 64;
  const int cb = blockIdx.y * 64;
  float acc[4][4] = {};
  for (int k0 = 0; k0 < 512; k0 += 16) {
    {
      const int idx = tid * 4;
      const int rl = idx >> 4;
      const int kk = idx & 15;
      float4 a4 = *(const float4*)(Yb + (size_t)(rb + rl) * 512 + k0 + kk);
      As[kk+0][rl] = a4.x; As[kk+1][rl] = a4.y; As[kk+2][rl] = a4.z; As[kk+3][rl] = a4.w;
    }
    {
      const int kk = tid >> 4;          // 0..15
      const int cl = (tid & 15) * 4;    // 0..60
      float4 b4 = *(const float4*)(wO + (size_t)(k0 + kk) * 1024 + cb + cl);
      Bs[kk][cl+0] = b4.x; Bs[kk][cl+1] = b4.y; Bs[kk][cl+2] = b4.z; Bs[kk][cl+3] = b4.w;
    }
    __syncthreads();
#pragma unroll
    for (int p = 0; p < 16; ++p) {
      float a[4], b[4];
#pragma unroll
      for (int i = 0; i < 4; ++i) a[i] = As[p][ty*4+i];
#pragma unroll
      for (int j = 0; j < 4; ++j) b[j] = Bs[p][tx*4+j];
#pragma unroll
      for (int i = 0; i < 4; ++i)
#pragma unroll
        for (int j = 0; j < 4; ++j)
          acc[i][j] = fmaf(a[i], b[j], acc[i][j]);
    }
    __syncthreads();
  }
#pragma unroll
  for (int i = 0; i < 4; ++i)
#pragma unroll
    for (int j = 0; j < 4; ++j)
      out[(size_t)(rb + ty*4 + i) * 1024 + cb + tx*4 + j] = acc[i][j];
}

extern "C" void kernel_launch(void* const* d_in, const int* in_sizes, int n_in,
                              void* d_out, int out_size, void* d_ws, size_t ws_size,
                              hipStream_t stream) {
  const float* X     = (const float*)d_in[0];
  const float* wG    = (const float*)d_in[1];
  const float* bG    = (const float*)d_in[2];
  const float* wK    = (const float*)d_in[3];
  const float* wV    = (const float*)d_in[4];
  const float* wQ    = (const float*)d_in[5];
  const float* wO    = (const float*)d_in[6];
  const float* initK = (const float*)d_in[7];
  const float* initV = (const float*)d_in[8];
  float* out = (float*)d_out;

  float* ws   = (float*)d_ws;
  float* Kb   = ws;                       // 2*8*2048*64  = 2,097,152
  float* Vb   = Kb   + 2097152;           // 2,097,152
  float* Qb   = Vb   + 2097152;           // 2,097,152
  float* Gb   = Qb   + 2097152;           // 2*8*4*2048   = 131,072
  float* recK = Gb   + 131072;            // 2*4*2080*64  = 1,064,960
  float* recV = recK + 1064960;           // 1,064,960
  float* Yb   = recV + 1064960;           // 4096*512     = 2,097,152
  // total 10,649,600 floats = 40.6 MiB of d_ws

  gemm_proj<<<dim3(64, 25), dim3(256), 0, stream>>>(X, wK, wV, wQ, wG, bG,
                                                    Kb, Vb, Qb, Gb);
  scan_kernel<<<dim3(8, 8, 2), dim3(64, 4), 0, stream>>>(Gb, Kb, Vb, initK, initV,
                                                         recK, recV);
  attn_kernel<<<dim3(2 * (2048 / BT)), dim3(512), 0, stream>>>(Qb, recK, recV, Yb);
  gemm_out<<<dim3(64, 16), dim3(256), 0, stream>>>(Yb, wO, out);
}

// Round 3
// 308.492 us; speedup vs baseline: 1.9368x; 1.9368x over previous
//
#include <hip/hip_runtime.h>
#include <math.h>

// Dims: N=2, T=2048, DM=1024, H=8, E=4, L=32, DK=DV=64
// Numerics note: the scan multiplier (1-sum_h G) has |.|~1.4, so rec grows to
// ~1e9 over 64 steps and softmax logits are ~1e8 (softmax==argmax). All GEMM
// inputs use split-bf16 (hi+lo, ~2^-17 effective) to avoid argmax flips;
// scan + attention stay f32.

typedef __attribute__((ext_vector_type(8))) short bf16x8;
typedef __attribute__((ext_vector_type(4))) float f32x4;

static __device__ __forceinline__ unsigned short f2bf(float f) {
  unsigned u = __float_as_uint(f);
  u += 0x7fffu + ((u >> 16) & 1u);   // RNE
  return (unsigned short)(u >> 16);
}
static __device__ __forceinline__ float bf2f(unsigned short h) {
  return __uint_as_float(((unsigned)h) << 16);
}

#define GLDS(gp, lp) \
  __builtin_amdgcn_global_load_lds((const __attribute__((address_space(1))) void*)(gp), \
                                   (__attribute__((address_space(3))) void*)(lp), 16, 0, 0)

// ---------------- converts (f32 -> hi/lo bf16 planes) ----------------
__global__ __launch_bounds__(256) void cvt_X_split(const float* __restrict__ X,
                                                   unsigned short* __restrict__ Xh,
                                                   unsigned short* __restrict__ Xl) {
  const int i = (blockIdx.x * 256 + threadIdx.x) * 4;  // < 4194304
  float4 v = *(const float4*)(X + i);
  ushort4 h, l;
  h.x = f2bf(v.x); l.x = f2bf(v.x - bf2f(h.x));
  h.y = f2bf(v.y); l.y = f2bf(v.y - bf2f(h.y));
  h.z = f2bf(v.z); l.z = f2bf(v.z - bf2f(h.z));
  h.w = f2bf(v.w); l.w = f2bf(v.w - bf2f(h.w));
  *(ushort4*)(Xh + i) = h;
  *(ushort4*)(Xl + i) = l;
}

// W rows: [0,512)=wK, [512,1024)=wV, [1024,1536)=wQ, [1536,1568)=wG, [1568,1664)=0
__global__ __launch_bounds__(256) void cvt_W_split(const float* __restrict__ wK,
                                                   const float* __restrict__ wV,
                                                   const float* __restrict__ wQ,
                                                   const float* __restrict__ wG,
                                                   unsigned short* __restrict__ Wh,
                                                   unsigned short* __restrict__ Wl) {
  const int idx = (blockIdx.x * 256 + threadIdx.x) * 4;  // < 1664*1024
  const int row = idx >> 10;
  const int col = idx & 1023;
  const float* src = nullptr;
  if (row < 512)       src = wK + (size_t)row * 1024;
  else if (row < 1024) src = wV + (size_t)(row - 512) * 1024;
  else if (row < 1536) src = wQ + (size_t)(row - 1024) * 1024;
  else if (row < 1568) src = wG + (size_t)(row - 1536) * 1024;
  float4 v = make_float4(0.f, 0.f, 0.f, 0.f);
  if (src) v = *(const float4*)(src + col);
  ushort4 h, l;
  h.x = f2bf(v.x); l.x = f2bf(v.x - bf2f(h.x));
  h.y = f2bf(v.y); l.y = f2bf(v.y - bf2f(h.y));
  h.z = f2bf(v.z); l.z = f2bf(v.z - bf2f(h.z));
  h.w = f2bf(v.w); l.w = f2bf(v.w - bf2f(h.w));
  *(ushort4*)(Wh + idx) = h;
  *(ushort4*)(Wl + idx) = l;
}

// wOt[n][k] = wO[k][n]  (512x1024 f32 -> 1024x512 hi/lo)
__global__ __launch_bounds__(256) void cvt_wOt_split(const float* __restrict__ wO,
                                                     unsigned short* __restrict__ wOth,
                                                     unsigned short* __restrict__ wOtl) {
  __shared__ float tile[32][33];
  const int tx = threadIdx.x;         // 0..31
  const int ty = threadIdx.y;         // 0..7
  const int n0 = blockIdx.x * 32;
  const int k0 = blockIdx.y * 32;
#pragma unroll
  for (int r = 0; r < 4; ++r)
    tile[ty * 4 + r][tx] = wO[(size_t)(k0 + ty * 4 + r) * 1024 + n0 + tx];
  __syncthreads();
#pragma unroll
  for (int r = 0; r < 4; ++r) {
    const float v = tile[tx][ty * 4 + r];
    const unsigned short h = f2bf(v);
    wOth[(size_t)(n0 + ty * 4 + r) * 512 + k0 + tx] = h;
    wOtl[(size_t)(n0 + ty * 4 + r) * 512 + k0 + tx] = f2bf(v - bf2f(h));
  }
}

// ---------------- K1: fused projection GEMM (split-bf16 MFMA) ----------------
// C[r][c] = sum_k X[r][k]*W[c][k]; M=4096, Ncols=1664(pad), K=1024
__global__ __launch_bounds__(256) void gemm_proj(
    const unsigned short* __restrict__ Xh, const unsigned short* __restrict__ Xl,
    const unsigned short* __restrict__ Wh, const unsigned short* __restrict__ Wl,
    const float* __restrict__ bG,
    float* __restrict__ Kb, float* __restrict__ Vb, float* __restrict__ Qb,
    float* __restrict__ Gb)
{
  __shared__ __align__(16) unsigned short Ash[128 * 32];
  __shared__ __align__(16) unsigned short Asl[128 * 32];
  __shared__ __align__(16) unsigned short Bsh[128 * 32];
  __shared__ __align__(16) unsigned short Bsl[128 * 32];
  const int tid  = threadIdx.x;
  const int lane = tid & 63;
  const int w    = tid >> 6;
  const int wr   = w >> 1, wc = w & 1;
  const int lm   = lane & 15, lq = lane >> 4;
  const int rb   = blockIdx.x * 128;
  const int cb   = blockIdx.y * 128;
  const int srow = lane >> 2;
  const int skc  = (lane & 3) * 8;

  f32x4 acc[4][4] = {};
  for (int k0 = 0; k0 < 1024; k0 += 32) {
#pragma unroll
    for (int q = 0; q < 2; ++q) {
      const int rbase = w * 32 + q * 16;
      const size_t ga = (size_t)(rb + rbase + srow) * 1024 + k0 + skc;
      const size_t gb = (size_t)(cb + rbase + srow) * 1024 + k0 + skc;
      GLDS(Xh + ga, Ash + rbase * 32);
      GLDS(Xl + ga, Asl + rbase * 32);
      GLDS(Wh + gb, Bsh + rbase * 32);
      GLDS(Wl + gb, Bsl + rbase * 32);
    }
    __syncthreads();
    bf16x8 ah[4], al[4], bh[4], bl[4];
#pragma unroll
    for (int i = 0; i < 4; ++i) {
      const int off = (wr * 64 + i * 16 + lm) * 32 + lq * 8;
      ah[i] = *(const bf16x8*)(Ash + off);
      al[i] = *(const bf16x8*)(Asl + off);
    }
#pragma unroll
    for (int j = 0; j < 4; ++j) {
      const int off = (wc * 64 + j * 16 + lm) * 32 + lq * 8;
      bh[j] = *(const bf16x8*)(Bsh + off);
      bl[j] = *(const bf16x8*)(Bsl + off);
    }
#pragma unroll
    for (int i = 0; i < 4; ++i)
#pragma unroll
      for (int j = 0; j < 4; ++j) {
        acc[i][j] = __builtin_amdgcn_mfma_f32_16x16x32_bf16(ah[i], bh[j], acc[i][j], 0, 0, 0);
        acc[i][j] = __builtin_amdgcn_mfma_f32_16x16x32_bf16(ah[i], bl[j], acc[i][j], 0, 0, 0);
        acc[i][j] = __builtin_amdgcn_mfma_f32_16x16x32_bf16(al[i], bh[j], acc[i][j], 0, 0, 0);
      }
    __syncthreads();
  }
#pragma unroll
  for (int i = 0; i < 4; ++i) {
#pragma unroll
    for (int j = 0; j < 4; ++j) {
      const int c = cb + wc * 64 + j * 16 + lm;
      if (c >= 1568) continue;
#pragma unroll
      for (int rr = 0; rr < 4; ++rr) {
        const int m = rb + wr * 64 + i * 16 + lq * 4 + rr;
        const int n = m >> 11, t = m & 2047;
        const float v = acc[i][j][rr];
        if (c < 512) {
          Kb[(size_t)((n * 8 + (c >> 6)) * 2048 + t) * 64 + (c & 63)] = v;
        } else if (c < 1024) {
          const int cc = c - 512;
          Vb[(size_t)((n * 8 + (cc >> 6)) * 2048 + t) * 64 + (cc & 63)] = v;
        } else if (c < 1536) {
          const int cc = c - 1024;
          Qb[(size_t)((n * 8 + (cc >> 6)) * 2048 + t) * 64 + (cc & 63)] = v;
        } else {
          const int cc = c - 1536;  // h*4+e
          const float g = 1.0f / (1.0f + __expf(-(v + bG[cc])));
          Gb[(size_t)(n * 32 + cc) * 2048 + t] = g;
        }
      }
    }
  }
}

// ---------------- K2: gated combine + lag-32 linear scan (f32) ----------------
__global__ __launch_bounds__(256) void scan_kernel(
    const float* __restrict__ Gb,    // (n,h,e,t)
    const float* __restrict__ Kb,    // (n,h,t,d)
    const float* __restrict__ Vb,
    const float* __restrict__ initK, // (E,32,64)
    const float* __restrict__ initV,
    float* __restrict__ recK,        // (n,e,2080,64)
    float* __restrict__ recV)
{
  const int d  = threadIdx.x;
  const int i  = blockIdx.y * blockDim.y + threadIdx.y;      // 0..31
  const int ne = blockIdx.x;
  const int n  = ne >> 2;
  const int e  = ne & 3;
  const bool isV = (blockIdx.z != 0);
  const float* src  = isV ? Vb : Kb;
  const float* init = isV ? initV : initK;
  float*       rec  = isV ? recV : recK;

  float y = init[(size_t)(e * 32 + i) * 64 + d];
  rec[(size_t)(ne * 2080 + i) * 64 + d] = y;
  const float* Gbase = Gb + (size_t)(n * 32 + e) * 2048;
  for (int j = 0; j < 64; ++j) {
    const int t = j * 32 + i;
    float gsum = 0.f, gx = 0.f;
#pragma unroll
    for (int h = 0; h < 8; ++h) {
      const float g = Gbase[(size_t)h * 8192 + t];
      gsum += g;
      gx = fmaf(g, src[(size_t)((n * 8 + h) * 2048 + t) * 64 + d], gx);
    }
    y = fmaf(1.0f - gsum, y, gx);
    rec[(size_t)(ne * 2080 + 32 + t) * 64 + d] = y;
  }
}

// ---------------- K3: sliding-window attention (f32) ----------------
#define BT 8
#define RR (BT + 31)   // 39 rows
__global__ __launch_bounds__(512) void attn_kernel(
    const float* __restrict__ Qb,    // (n,h,t,64)
    const float* __restrict__ recK,  // (n,e,2080,64)
    const float* __restrict__ recV,
    unsigned short* __restrict__ Ybh,  // bf16 hi (n*T, 512); col = h*64+d
    unsigned short* __restrict__ Ybl)  // bf16 lo
{
  __shared__ float Ks[4 * RR * 65];
  __shared__ float Vs[4 * RR * 65];
  __shared__ float Qs[8][BT][64];
  const int tid  = threadIdx.x;
  const int lane = tid & 63;
  const int w    = tid >> 6;
  const int bx   = blockIdx.x;
  const int n    = bx / (2048 / BT);
  const int t0   = (bx % (2048 / BT)) * BT;

  for (int idx = tid; idx < 4 * RR * 64; idx += 512) {
    const int d = idx & 63;
    const int r = (idx >> 6) % RR;
    const int e = (idx >> 6) / RR;
    const int s = t0 + 1 + r;
    const size_t g = (size_t)((n * 4 + e) * 2080 + s) * 64 + d;
    Ks[(e * RR + r) * 65 + d] = recK[g];
    Vs[(e * RR + r) * 65 + d] = recV[g];
  }
  for (int idx = tid; idx < 8 * BT * 64; idx += 512) {
    const int d  = idx & 63;
    const int tl = (idx >> 6) % BT;
    const int h  = (idx >> 6) / BT;
    Qs[h][tl][d] = Qb[(size_t)((n * 8 + h) * 2048 + t0 + tl) * 64 + d];
  }
  __syncthreads();

  const int t  = t0 + w;
  const int e0 = lane >> 5, i0 = lane & 31;
  const int r0 = (e0 * RR + (w + i0)) * 65;
  const int r1 = ((e0 + 2) * RR + (w + i0)) * 65;

  for (int h = 0; h < 8; ++h) {
    float s0 = 0.f, s1 = 0.f;
#pragma unroll 8
    for (int d = 0; d < 64; ++d) {
      const float q = Qs[h][w][d];
      s0 = fmaf(q, Ks[r0 + d], s0);
      s1 = fmaf(q, Ks[r1 + d], s1);
    }
    s0 *= 0.125f; s1 *= 0.125f;
    float m = fmaxf(s0, s1);
    for (int off = 32; off; off >>= 1) m = fmaxf(m, __shfl_xor(m, off));
    float p0 = __expf(s0 - m), p1 = __expf(s1 - m);
    float sum = p0 + p1;
    for (int off = 32; off; off >>= 1) sum += __shfl_xor(sum, off);
    const float inv = 1.0f / sum;
    p0 *= inv; p1 *= inv;
    float acc = 0.f;
#pragma unroll 8
    for (int ei = 0; ei < 64; ++ei) {
      const float a = __shfl(p0, ei);
      const int e = ei >> 5, ii = ei & 31;
      acc = fmaf(a, Vs[(e * RR + w + ii) * 65 + lane], acc);
    }
#pragma unroll 8
    for (int ei = 0; ei < 64; ++ei) {
      const float a = __shfl(p1, ei);
      const int e = 2 + (ei >> 5), ii = ei & 31;
      acc = fmaf(a, Vs[(e * RR + w + ii) * 65 + lane], acc);
    }
    const size_t oi = (size_t)(n * 2048 + t) * 512 + h * 64 + lane;
    const unsigned short hh = f2bf(acc);
    Ybh[oi] = hh;
    Ybl[oi] = f2bf(acc - bf2f(hh));
  }
}

// ---------------- K4: output GEMM (split-bf16 MFMA) ----------------
// out[r][c] = sum_k Y[r][k]*wOt[c][k]; M=4096, N=1024, K=512
__global__ __launch_bounds__(256) void gemm_out(
    const unsigned short* __restrict__ Yh, const unsigned short* __restrict__ Yl,
    const unsigned short* __restrict__ Wh, const unsigned short* __restrict__ Wl,
    float* __restrict__ out)
{
  __shared__ __align__(16) unsigned short Ash[128 * 32];
  __shared__ __align__(16) unsigned short Asl[128 * 32];
  __shared__ __align__(16) unsigned short Bsh[128 * 32];
  __shared__ __align__(16) unsigned short Bsl[128 * 32];
  const int tid  = threadIdx.x;
  const int lane = tid & 63;
  const int w    = tid >> 6;
  const int wr   = w >> 1, wc = w & 1;
  const int lm   = lane & 15, lq = lane >> 4;
  const int rb   = blockIdx.x * 128;
  const int cb   = blockIdx.y * 128;
  const int srow = lane >> 2;
  const int skc  = (lane & 3) * 8;

  f32x4 acc[4][4] = {};
  for (int k0 = 0; k0 < 512; k0 += 32) {
#pragma unroll
    for (int q = 0; q < 2; ++q) {
      const int rbase = w * 32 + q * 16;
      const size_t ga = (size_t)(rb + rbase + srow) * 512 + k0 + skc;
      const size_t gb = (size_t)(cb + rbase + srow) * 512 + k0 + skc;
      GLDS(Yh + ga, Ash + rbase * 32);
      GLDS(Yl + ga, Asl + rbase * 32);
      GLDS(Wh + gb, Bsh + rbase * 32);
      GLDS(Wl + gb, Bsl + rbase * 32);
    }
    __syncthreads();
    bf16x8 ah[4], al[4], bh[4], bl[4];
#pragma unroll
    for (int i = 0; i < 4; ++i) {
      const int off = (wr * 64 + i * 16 + lm) * 32 + lq * 8;
      ah[i] = *(const bf16x8*)(Ash + off);
      al[i] = *(const bf16x8*)(Asl + off);
    }
#pragma unroll
    for (int j = 0; j < 4; ++j) {
      const int off = (wc * 64 + j * 16 + lm) * 32 + lq * 8;
      bh[j] = *(const bf16x8*)(Bsh + off);
      bl[j] = *(const bf16x8*)(Bsl + off);
    }
#pragma unroll
    for (int i = 0; i < 4; ++i)
#pragma unroll
      for (int j = 0; j < 4; ++j) {
        acc[i][j] = __builtin_amdgcn_mfma_f32_16x16x32_bf16(ah[i], bh[j], acc[i][j], 0, 0, 0);
        acc[i][j] = __builtin_amdgcn_mfma_f32_16x16x32_bf16(ah[i], bl[j], acc[i][j], 0, 0, 0);
        acc[i][j] = __builtin_amdgcn_mfma_f32_16x16x32_bf16(al[i], bh[j], acc[i][j], 0, 0, 0);
      }
    __syncthreads();
  }
#pragma unroll
  for (int i = 0; i < 4; ++i)
#pragma unroll
    for (int j = 0; j < 4; ++j)
#pragma unroll
      for (int rr = 0; rr < 4; ++rr) {
        const int m = rb + wr * 64 + i * 16 + lq * 4 + rr;
        const int c = cb + wc * 64 + j * 16 + lm;
        out[(size_t)m * 1024 + c] = acc[i][j][rr];
      }
}

extern "C" void kernel_launch(void* const* d_in, const int* in_sizes, int n_in,
                              void* d_out, int out_size, void* d_ws, size_t ws_size,
                              hipStream_t stream) {
  const float* X     = (const float*)d_in[0];
  const float* wG    = (const float*)d_in[1];
  const float* bG    = (const float*)d_in[2];
  const float* wK    = (const float*)d_in[3];
  const float* wV    = (const float*)d_in[4];
  const float* wQ    = (const float*)d_in[5];
  const float* wO    = (const float*)d_in[6];
  const float* initK = (const float*)d_in[7];
  const float* initV = (const float*)d_in[8];
  float* out = (float*)d_out;

  // --- workspace layout (51.4 MB total, with aliasing) ---
  float* ws = (float*)d_ws;
  float* Kb = ws;                    // 2,097,152 f
  float* Vb = Kb + 2097152;          // 2,097,152 f
  float* Qb = Vb + 2097152;          // 2,097,152 f
  float* Gb = Qb + 2097152;          //   131,072 f
  unsigned short* Xh   = (unsigned short*)(Gb + 131072);  // 4,194,304 s
  unsigned short* Xl   = Xh + 4194304;                    // 4,194,304 s
  unsigned short* Wh   = Xl + 4194304;                    // 1,703,936 s
  unsigned short* Wl   = Wh + 1703936;                    // 1,703,936 s
  unsigned short* wOth = Wl + 1703936;                    //   524,288 s
  unsigned short* wOtl = wOth + 524288;                   //   524,288 s
  // aliases (lifetimes don't overlap):
  float* recK = (float*)Xh;          // 1,064,960 f (X planes dead after gemm_proj)
  float* recV = recK + 1064960;      // 1,064,960 f (fits in Xh+Xl region)
  unsigned short* Ybh = (unsigned short*)Kb;  // 2,097,152 s (Kb dead after scan)
  unsigned short* Ybl = Ybh + 2097152;        // 2,097,152 s (exactly fills Kb)

  cvt_X_split<<<dim3(4096), dim3(256), 0, stream>>>(X, Xh, Xl);
  cvt_W_split<<<dim3(1664), dim3(256), 0, stream>>>(wK, wV, wQ, wG, Wh, Wl);
  cvt_wOt_split<<<dim3(32, 16), dim3(32, 8), 0, stream>>>(wO, wOth, wOtl);
  gemm_proj<<<dim3(32, 13), dim3(256), 0, stream>>>(Xh, Xl, Wh, Wl, bG, Kb, Vb, Qb, Gb);
  scan_kernel<<<dim3(8, 8, 2), dim3(64, 4), 0, stream>>>(Gb, Kb, Vb, initK, initV,
                                                         recK, recV);
  attn_kernel<<<dim3(2 * (2048 / BT)), dim3(512), 0, stream>>>(Qb, recK, recV, Ybh, Ybl);
  gemm_out<<<dim3(32, 8), dim3(256), 0, stream>>>(Ybh, Ybl, wOth, wOtl, out);
}

// Round 4
// 222.631 us; speedup vs baseline: 2.6837x; 1.3857x over previous
//
#include <hip/hip_runtime.h>
#include <math.h>

// Dims: N=2, T=2048, DM=1024, H=8, E=4, L=32, DK=DV=64
// Numerics: scan multiplier (1-sum_h G) ~ -1.4 => rec ~1e9, logits ~1e8
// (softmax==argmax). All GEMM-ish paths use split-bf16 (hi+lo, ~2^-17 eff).

typedef __attribute__((ext_vector_type(8))) short bf16x8;
typedef __attribute__((ext_vector_type(4))) float f32x4;

static __device__ __forceinline__ unsigned short f2bf(float f) {
  unsigned u = __float_as_uint(f);
  u += 0x7fffu + ((u >> 16) & 1u);   // RNE
  return (unsigned short)(u >> 16);
}
static __device__ __forceinline__ float bf2f(unsigned short h) {
  return __uint_as_float(((unsigned)h) << 16);
}
static __device__ __forceinline__ unsigned packbf(float f) {
  unsigned short h = f2bf(f);
  unsigned short l = f2bf(f - bf2f(h));
  return ((unsigned)h << 16) | (unsigned)l;
}

#define GLDS(gp, lp) \
  __builtin_amdgcn_global_load_lds((const __attribute__((address_space(1))) void*)(gp), \
                                   (__attribute__((address_space(3))) void*)(lp), 16, 0, 0)

// ---------------- converts (f32 -> hi/lo bf16 planes) ----------------
__global__ __launch_bounds__(256) void cvt_X_split(const float* __restrict__ X,
                                                   unsigned short* __restrict__ Xh,
                                                   unsigned short* __restrict__ Xl) {
  const int i = (blockIdx.x * 256 + threadIdx.x) * 4;
  float4 v = *(const float4*)(X + i);
  ushort4 h, l;
  h.x = f2bf(v.x); l.x = f2bf(v.x - bf2f(h.x));
  h.y = f2bf(v.y); l.y = f2bf(v.y - bf2f(h.y));
  h.z = f2bf(v.z); l.z = f2bf(v.z - bf2f(h.z));
  h.w = f2bf(v.w); l.w = f2bf(v.w - bf2f(h.w));
  *(ushort4*)(Xh + i) = h;
  *(ushort4*)(Xl + i) = l;
}

__global__ __launch_bounds__(256) void cvt_W_split(const float* __restrict__ wK,
                                                   const float* __restrict__ wV,
                                                   const float* __restrict__ wQ,
                                                   const float* __restrict__ wG,
                                                   unsigned short* __restrict__ Wh,
                                                   unsigned short* __restrict__ Wl) {
  const int idx = (blockIdx.x * 256 + threadIdx.x) * 4;
  const int row = idx >> 10;
  const int col = idx & 1023;
  const float* src = nullptr;
  if (row < 512)       src = wK + (size_t)row * 1024;
  else if (row < 1024) src = wV + (size_t)(row - 512) * 1024;
  else if (row < 1536) src = wQ + (size_t)(row - 1024) * 1024;
  else if (row < 1568) src = wG + (size_t)(row - 1536) * 1024;
  float4 v = make_float4(0.f, 0.f, 0.f, 0.f);
  if (src) v = *(const float4*)(src + col);
  ushort4 h, l;
  h.x = f2bf(v.x); l.x = f2bf(v.x - bf2f(h.x));
  h.y = f2bf(v.y); l.y = f2bf(v.y - bf2f(h.y));
  h.z = f2bf(v.z); l.z = f2bf(v.z - bf2f(h.z));
  h.w = f2bf(v.w); l.w = f2bf(v.w - bf2f(h.w));
  *(ushort4*)(Wh + idx) = h;
  *(ushort4*)(Wl + idx) = l;
}

__global__ __launch_bounds__(256) void cvt_wOt_split(const float* __restrict__ wO,
                                                     unsigned short* __restrict__ wOth,
                                                     unsigned short* __restrict__ wOtl) {
  __shared__ float tile[32][33];
  const int tx = threadIdx.x;
  const int ty = threadIdx.y;
  const int n0 = blockIdx.x * 32;
  const int k0 = blockIdx.y * 32;
#pragma unroll
  for (int r = 0; r < 4; ++r)
    tile[ty * 4 + r][tx] = wO[(size_t)(k0 + ty * 4 + r) * 1024 + n0 + tx];
  __syncthreads();
#pragma unroll
  for (int r = 0; r < 4; ++r) {
    const float v = tile[tx][ty * 4 + r];
    const unsigned short h = f2bf(v);
    wOth[(size_t)(n0 + ty * 4 + r) * 512 + k0 + tx] = h;
    wOtl[(size_t)(n0 + ty * 4 + r) * 512 + k0 + tx] = f2bf(v - bf2f(h));
  }
}

// ---------------- K1: fused projection GEMM (split-bf16 MFMA) ----------------
__global__ __launch_bounds__(256) void gemm_proj(
    const unsigned short* __restrict__ Xh, const unsigned short* __restrict__ Xl,
    const unsigned short* __restrict__ Wh, const unsigned short* __restrict__ Wl,
    const float* __restrict__ bG,
    float* __restrict__ Kb, float* __restrict__ Vb, float* __restrict__ Qb,
    float* __restrict__ Gb)
{
  __shared__ __align__(16) unsigned short Ash[128 * 32];
  __shared__ __align__(16) unsigned short Asl[128 * 32];
  __shared__ __align__(16) unsigned short Bsh[128 * 32];
  __shared__ __align__(16) unsigned short Bsl[128 * 32];
  const int tid  = threadIdx.x;
  const int lane = tid & 63;
  const int w    = tid >> 6;
  const int wr   = w >> 1, wc = w & 1;
  const int lm   = lane & 15, lq = lane >> 4;
  const int rb   = blockIdx.x * 128;
  const int cb   = blockIdx.y * 128;
  const int srow = lane >> 2;
  const int skc  = (lane & 3) * 8;

  f32x4 acc[4][4] = {};
  for (int k0 = 0; k0 < 1024; k0 += 32) {
#pragma unroll
    for (int q = 0; q < 2; ++q) {
      const int rbase = w * 32 + q * 16;
      const size_t ga = (size_t)(rb + rbase + srow) * 1024 + k0 + skc;
      const size_t gb = (size_t)(cb + rbase + srow) * 1024 + k0 + skc;
      GLDS(Xh + ga, Ash + rbase * 32);
      GLDS(Xl + ga, Asl + rbase * 32);
      GLDS(Wh + gb, Bsh + rbase * 32);
      GLDS(Wl + gb, Bsl + rbase * 32);
    }
    __syncthreads();
    bf16x8 ah[4], al[4], bh[4], bl[4];
#pragma unroll
    for (int i = 0; i < 4; ++i) {
      const int off = (wr * 64 + i * 16 + lm) * 32 + lq * 8;
      ah[i] = *(const bf16x8*)(Ash + off);
      al[i] = *(const bf16x8*)(Asl + off);
    }
#pragma unroll
    for (int j = 0; j < 4; ++j) {
      const int off = (wc * 64 + j * 16 + lm) * 32 + lq * 8;
      bh[j] = *(const bf16x8*)(Bsh + off);
      bl[j] = *(const bf16x8*)(Bsl + off);
    }
#pragma unroll
    for (int i = 0; i < 4; ++i)
#pragma unroll
      for (int j = 0; j < 4; ++j) {
        acc[i][j] = __builtin_amdgcn_mfma_f32_16x16x32_bf16(ah[i], bh[j], acc[i][j], 0, 0, 0);
        acc[i][j] = __builtin_amdgcn_mfma_f32_16x16x32_bf16(ah[i], bl[j], acc[i][j], 0, 0, 0);
        acc[i][j] = __builtin_amdgcn_mfma_f32_16x16x32_bf16(al[i], bh[j], acc[i][j], 0, 0, 0);
      }
    __syncthreads();
  }
#pragma unroll
  for (int i = 0; i < 4; ++i) {
#pragma unroll
    for (int j = 0; j < 4; ++j) {
      const int c = cb + wc * 64 + j * 16 + lm;
      if (c >= 1568) continue;
#pragma unroll
      for (int rr = 0; rr < 4; ++rr) {
        const int m = rb + wr * 64 + i * 16 + lq * 4 + rr;
        const int n = m >> 11, t = m & 2047;
        const float v = acc[i][j][rr];
        if (c < 512) {
          Kb[(size_t)((n * 8 + (c >> 6)) * 2048 + t) * 64 + (c & 63)] = v;
        } else if (c < 1024) {
          const int cc = c - 512;
          Vb[(size_t)((n * 8 + (cc >> 6)) * 2048 + t) * 64 + (cc & 63)] = v;
        } else if (c < 1536) {
          const int cc = c - 1024;
          Qb[(size_t)((n * 8 + (cc >> 6)) * 2048 + t) * 64 + (cc & 63)] = v;
        } else {
          const int cc = c - 1536;  // h*4+e
          const float g = 1.0f / (1.0f + __expf(-(v + bG[cc])));
          Gb[(size_t)(n * 32 + cc) * 2048 + t] = g;
        }
      }
    }
  }
}

// ---------------- K2: gated combine + lag-32 scan; emits packed bf16 hi/lo ---
__global__ __launch_bounds__(256) void scan_kernel(
    const float* __restrict__ Gb,    // (n,h,e,t)
    const float* __restrict__ Kb,    // (n,h,t,d)
    const float* __restrict__ Vb,
    const float* __restrict__ initK, // (E,32,64)
    const float* __restrict__ initV,
    unsigned* __restrict__ recK,     // (n,e,2080,64) packed (hi<<16)|lo
    unsigned* __restrict__ recV)
{
  const int d  = threadIdx.x;
  const int i  = blockIdx.y * blockDim.y + threadIdx.y;      // 0..31
  const int ne = blockIdx.x;
  const int n  = ne >> 2;
  const int e  = ne & 3;
  const bool isV = (blockIdx.z != 0);
  const float* src  = isV ? Vb : Kb;
  const float* init = isV ? initV : initK;
  unsigned*    rec  = isV ? recV : recK;

  float y = init[(size_t)(e * 32 + i) * 64 + d];
  rec[(size_t)(ne * 2080 + i) * 64 + d] = packbf(y);
  const float* Gbase = Gb + (size_t)(n * 32 + e) * 2048;
  for (int j = 0; j < 64; ++j) {
    const int t = j * 32 + i;
    float gsum = 0.f, gx = 0.f;
#pragma unroll
    for (int h = 0; h < 8; ++h) {
      const float g = Gbase[(size_t)h * 8192 + t];
      gsum += g;
      gx = fmaf(g, src[(size_t)((n * 8 + h) * 2048 + t) * 64 + d], gx);
    }
    y = fmaf(1.0f - gsum, y, gx);
    rec[(size_t)(ne * 2080 + 32 + t) * 64 + d] = packbf(y);
  }
}

// ---------------- K3: banded MFMA attention ----------------
// Block: (n, t0=16 t-rows), 512 thr = 8 waves (wave=head).
// Key window per e: s = t0+1 .. t0+48 (48 rows). Band: 1<=s-t<=32.
// LDS (shorts): Ks hi/lo [48][72], Vt hi/lo [64][56] (V transposed), per-wave
// P hi/lo [16][72]. Total 65,024 B.
#define TB 16
__global__ __launch_bounds__(512) void attn_kernel(
    const float* __restrict__ Qb,       // (n,h,t,64) f32
    const unsigned* __restrict__ recK,  // (n,e,2080,64) packed
    const unsigned* __restrict__ recV,
    unsigned short* __restrict__ Ybh,   // (n*T,512) hi
    unsigned short* __restrict__ Ybl)   // lo
{
  __shared__ __align__(16) unsigned short lds[32512];
  const int KS_HI = 0;            // 48*72 = 3456
  const int KS_LO = 3456;
  const int VT_HI = 6912;         // 64*56 = 3584
  const int VT_LO = 10496;
  const int PW0   = 14080;        // 8 waves * 16*72 per plane

  const int tid  = threadIdx.x;
  const int lane = tid & 63;
  const int w    = tid >> 6;           // head
  const int lm   = lane & 15, lq = lane >> 4;
  const int n    = blockIdx.x >> 7;
  const int t0   = (blockIdx.x & 127) * TB;
  const int maxidx = (2078 - t0) * 64 + 63;   // clamp staging reads to s<=2079

  // Q A-frags (hi/lo x 2 ksteps) straight from global
  bf16x8 aqh[2], aql[2];
  {
    const float* qrow = Qb + ((size_t)(n * 8 + w) * 2048 + t0 + lm) * 64 + lq * 8;
#pragma unroll
    for (int ks = 0; ks < 2; ++ks) {
      float4 q0 = *(const float4*)(qrow + ks * 32);
      float4 q1 = *(const float4*)(qrow + ks * 32 + 4);
      float qv[8] = {q0.x, q0.y, q0.z, q0.w, q1.x, q1.y, q1.z, q1.w};
#pragma unroll
      for (int j = 0; j < 8; ++j) {
        unsigned short h = f2bf(qv[j]);
        aqh[ks][j] = (short)h;
        aql[ks][j] = (short)f2bf(qv[j] - bf2f(h));
      }
    }
  }

  // ---- Phase A: scores for all 4 experts ----
  f32x4 S[4][3];
  for (int e = 0; e < 4; ++e) {
    __syncthreads();
    {
      const unsigned* src = recK + ((size_t)(n * 4 + e) * 2080 + t0 + 1) * 64;
#pragma unroll
      for (int p = 0; p < 6; ++p) {
        const int idx = tid + p * 512;
        const int sl = idx >> 6, d = idx & 63;
        const unsigned u = src[idx <= maxidx ? idx : maxidx];
        lds[KS_HI + sl * 72 + d] = (unsigned short)(u >> 16);
        lds[KS_LO + sl * 72 + d] = (unsigned short)(u & 0xffffu);
      }
    }
    __syncthreads();
#pragma unroll
    for (int j = 0; j < 3; ++j) {
      f32x4 s = {0.f, 0.f, 0.f, 0.f};
#pragma unroll
      for (int ks = 0; ks < 2; ++ks) {
        const int boff = (j * 16 + lm) * 72 + ks * 32 + lq * 8;
        bf16x8 bh = *(const bf16x8*)(lds + KS_HI + boff);
        bf16x8 bl = *(const bf16x8*)(lds + KS_LO + boff);
        s = __builtin_amdgcn_mfma_f32_16x16x32_bf16(aqh[ks], bh, s, 0, 0, 0);
        s = __builtin_amdgcn_mfma_f32_16x16x32_bf16(aqh[ks], bl, s, 0, 0, 0);
        s = __builtin_amdgcn_mfma_f32_16x16x32_bf16(aql[ks], bh, s, 0, 0, 0);
      }
      S[e][j] = s;
    }
  }

  // ---- Phase B: mask + softmax (C layout: row=lq*4+rr, col=lm) ----
  const float NEG = -3.0e38f;
  float mx[4] = {NEG, NEG, NEG, NEG};
#pragma unroll
  for (int e = 0; e < 4; ++e)
#pragma unroll
    for (int j = 0; j < 3; ++j) {
      const int sl = j * 16 + lm;
#pragma unroll
      for (int rr = 0; rr < 4; ++rr) {
        const int m = lq * 4 + rr;
        const bool valid = ((unsigned)(sl - m) <= 31u);
        const float v = valid ? S[e][j][rr] * 0.125f : NEG;
        S[e][j][rr] = v;
        mx[rr] = fmaxf(mx[rr], v);
      }
    }
#pragma unroll
  for (int rr = 0; rr < 4; ++rr) {
    float m = mx[rr];
    m = fmaxf(m, __shfl_xor(m, 1));
    m = fmaxf(m, __shfl_xor(m, 2));
    m = fmaxf(m, __shfl_xor(m, 4));
    m = fmaxf(m, __shfl_xor(m, 8));
    mx[rr] = m;
  }
  float sm[4] = {0.f, 0.f, 0.f, 0.f};
#pragma unroll
  for (int e = 0; e < 4; ++e)
#pragma unroll
    for (int j = 0; j < 3; ++j)
#pragma unroll
      for (int rr = 0; rr < 4; ++rr) {
        const float p = __expf(S[e][j][rr] - mx[rr]);
        S[e][j][rr] = p;
        sm[rr] += p;
      }
  float inv[4];
#pragma unroll
  for (int rr = 0; rr < 4; ++rr) {
    float s = sm[rr];
    s += __shfl_xor(s, 1);
    s += __shfl_xor(s, 2);
    s += __shfl_xor(s, 4);
    s += __shfl_xor(s, 8);
    inv[rr] = 1.0f / s;
  }

  // ---- Phase C: PV ----
  const int PWH = PW0 + w * 1152;
  const int PWL = PW0 + 9216 + w * 1152;
  {  // zero P pad cols 48..63 once (k-pad read by MFMA, must be 0)
    const int r = lane >> 2, c0 = 48 + (lane & 3) * 4;
#pragma unroll
    for (int c = 0; c < 4; ++c) {
      lds[PWH + r * 72 + c0 + c] = 0;
      lds[PWL + r * 72 + c0 + c] = 0;
    }
  }
  f32x4 O[4] = {};
  for (int e = 0; e < 4; ++e) {
    __syncthreads();
    {
      const unsigned* src = recV + ((size_t)(n * 4 + e) * 2080 + t0 + 1) * 64;
#pragma unroll
      for (int p = 0; p < 6; ++p) {
        const int idx = tid + p * 512;
        const int sl = idx >> 6, d = idx & 63;
        const unsigned u = src[idx <= maxidx ? idx : maxidx];
        lds[VT_HI + d * 56 + sl] = (unsigned short)(u >> 16);
        lds[VT_LO + d * 56 + sl] = (unsigned short)(u & 0xffffu);
      }
    }
    // write normalized P_e into this wave's scratch
#pragma unroll
    for (int j = 0; j < 3; ++j)
#pragma unroll
      for (int rr = 0; rr < 4; ++rr) {
        const float p = S[e][j][rr] * inv[rr];
        const unsigned short h = f2bf(p);
        lds[PWH + (lq * 4 + rr) * 72 + j * 16 + lm] = h;
        lds[PWL + (lq * 4 + rr) * 72 + j * 16 + lm] = f2bf(p - bf2f(h));
      }
    __syncthreads();
    bf16x8 ah[2], al[2];
#pragma unroll
    for (int ks = 0; ks < 2; ++ks) {
      ah[ks] = *(const bf16x8*)(lds + PWH + lm * 72 + ks * 32 + lq * 8);
      al[ks] = *(const bf16x8*)(lds + PWL + lm * 72 + ks * 32 + lq * 8);
    }
#pragma unroll
    for (int nt = 0; nt < 4; ++nt)
#pragma unroll
      for (int ks = 0; ks < 2; ++ks) {
        const int boff = (nt * 16 + lm) * 56 + ks * 32 + lq * 8;
        bf16x8 vh = *(const bf16x8*)(lds + VT_HI + boff);
        bf16x8 vl = *(const bf16x8*)(lds + VT_LO + boff);
        O[nt] = __builtin_amdgcn_mfma_f32_16x16x32_bf16(ah[ks], vh, O[nt], 0, 0, 0);
        O[nt] = __builtin_amdgcn_mfma_f32_16x16x32_bf16(ah[ks], vl, O[nt], 0, 0, 0);
        O[nt] = __builtin_amdgcn_mfma_f32_16x16x32_bf16(al[ks], vh, O[nt], 0, 0, 0);
      }
  }

  // ---- epilogue: Y hi/lo ----
#pragma unroll
  for (int nt = 0; nt < 4; ++nt)
#pragma unroll
    for (int rr = 0; rr < 4; ++rr) {
      const int t = t0 + lq * 4 + rr;
      const size_t oi = ((size_t)(n * 2048 + t)) * 512 + w * 64 + nt * 16 + lm;
      const float v = O[nt][rr];
      const unsigned short h = f2bf(v);
      Ybh[oi] = h;
      Ybl[oi] = f2bf(v - bf2f(h));
    }
}

// ---------------- K4: output GEMM (split-bf16 MFMA) ----------------
__global__ __launch_bounds__(256) void gemm_out(
    const unsigned short* __restrict__ Yh, const unsigned short* __restrict__ Yl,
    const unsigned short* __restrict__ Wh, const unsigned short* __restrict__ Wl,
    float* __restrict__ out)
{
  __shared__ __align__(16) unsigned short Ash[128 * 32];
  __shared__ __align__(16) unsigned short Asl[128 * 32];
  __shared__ __align__(16) unsigned short Bsh[128 * 32];
  __shared__ __align__(16) unsigned short Bsl[128 * 32];
  const int tid  = threadIdx.x;
  const int lane = tid & 63;
  const int w    = tid >> 6;
  const int wr   = w >> 1, wc = w & 1;
  const int lm   = lane & 15, lq = lane >> 4;
  const int rb   = blockIdx.x * 128;
  const int cb   = blockIdx.y * 128;
  const int srow = lane >> 2;
  const int skc  = (lane & 3) * 8;

  f32x4 acc[4][4] = {};
  for (int k0 = 0; k0 < 512; k0 += 32) {
#pragma unroll
    for (int q = 0; q < 2; ++q) {
      const int rbase = w * 32 + q * 16;
      const size_t ga = (size_t)(rb + rbase + srow) * 512 + k0 + skc;
      const size_t gb = (size_t)(cb + rbase + srow) * 512 + k0 + skc;
      GLDS(Yh + ga, Ash + rbase * 32);
      GLDS(Yl + ga, Asl + rbase * 32);
      GLDS(Wh + gb, Bsh + rbase * 32);
      GLDS(Wl + gb, Bsl + rbase * 32);
    }
    __syncthreads();
    bf16x8 ah[4], al[4], bh[4], bl[4];
#pragma unroll
    for (int i = 0; i < 4; ++i) {
      const int off = (wr * 64 + i * 16 + lm) * 32 + lq * 8;
      ah[i] = *(const bf16x8*)(Ash + off);
      al[i] = *(const bf16x8*)(Asl + off);
    }
#pragma unroll
    for (int j = 0; j < 4; ++j) {
      const int off = (wc * 64 + j * 16 + lm) * 32 + lq * 8;
      bh[j] = *(const bf16x8*)(Bsh + off);
      bl[j] = *(const bf16x8*)(Bsl + off);
    }
#pragma unroll
    for (int i = 0; i < 4; ++i)
#pragma unroll
      for (int j = 0; j < 4; ++j) {
        acc[i][j] = __builtin_amdgcn_mfma_f32_16x16x32_bf16(ah[i], bh[j], acc[i][j], 0, 0, 0);
        acc[i][j] = __builtin_amdgcn_mfma_f32_16x16x32_bf16(ah[i], bl[j], acc[i][j], 0, 0, 0);
        acc[i][j] = __builtin_amdgcn_mfma_f32_16x16x32_bf16(al[i], bh[j], acc[i][j], 0, 0, 0);
      }
    __syncthreads();
  }
#pragma unroll
  for (int i = 0; i < 4; ++i)
#pragma unroll
    for (int j = 0; j < 4; ++j)
#pragma unroll
      for (int rr = 0; rr < 4; ++rr) {
        const int m = rb + wr * 64 + i * 16 + lq * 4 + rr;
        const int c = cb + wc * 64 + j * 16 + lm;
        out[(size_t)m * 1024 + c] = acc[i][j][rr];
      }
}

extern "C" void kernel_launch(void* const* d_in, const int* in_sizes, int n_in,
                              void* d_out, int out_size, void* d_ws, size_t ws_size,
                              hipStream_t stream) {
  const float* X     = (const float*)d_in[0];
  const float* wG    = (const float*)d_in[1];
  const float* bG    = (const float*)d_in[2];
  const float* wK    = (const float*)d_in[3];
  const float* wV    = (const float*)d_in[4];
  const float* wQ    = (const float*)d_in[5];
  const float* wO    = (const float*)d_in[6];
  const float* initK = (const float*)d_in[7];
  const float* initV = (const float*)d_in[8];
  float* out = (float*)d_out;

  // --- workspace layout (with lifetime aliasing) ---
  float* ws = (float*)d_ws;
  float* Kb = ws;                    // 2,097,152 f
  float* Vb = Kb + 2097152;          // 2,097,152 f
  float* Qb = Vb + 2097152;          // 2,097,152 f
  float* Gb = Qb + 2097152;          //   131,072 f
  unsigned short* Xh   = (unsigned short*)(Gb + 131072);  // 4,194,304 s
  unsigned short* Xl   = Xh + 4194304;                    // 4,194,304 s
  unsigned short* Wh   = Xl + 4194304;                    // 1,703,936 s
  unsigned short* Wl   = Wh + 1703936;                    // 1,703,936 s
  unsigned short* wOth = Wl + 1703936;                    //   524,288 s
  unsigned short* wOtl = wOth + 524288;                   //   524,288 s
  // aliases (lifetimes don't overlap):
  unsigned* recK = (unsigned*)Xh;    // 1,064,960 u (X planes dead after gemm_proj)
  unsigned* recV = recK + 1064960;   // 1,064,960 u
  unsigned short* Ybh = (unsigned short*)Kb;  // 2,097,152 s (Kb dead after scan)
  unsigned short* Ybl = Ybh + 2097152;

  cvt_X_split<<<dim3(4096), dim3(256), 0, stream>>>(X, Xh, Xl);
  cvt_W_split<<<dim3(1664), dim3(256), 0, stream>>>(wK, wV, wQ, wG, Wh, Wl);
  cvt_wOt_split<<<dim3(32, 16), dim3(32, 8), 0, stream>>>(wO, wOth, wOtl);
  gemm_proj<<<dim3(32, 13), dim3(256), 0, stream>>>(Xh, Xl, Wh, Wl, bG, Kb, Vb, Qb, Gb);
  scan_kernel<<<dim3(8, 8, 2), dim3(64, 4), 0, stream>>>(Gb, Kb, Vb, initK, initV,
                                                         recK, recV);
  attn_kernel<<<dim3(256), dim3(512), 0, stream>>>(Qb, recK, recV, Ybh, Ybl);
  gemm_out<<<dim3(32, 8), dim3(256), 0, stream>>>(Ybh, Ybl, wOth, wOtl, out);
}

// Round 5
// 198.500 us; speedup vs baseline: 3.0099x; 1.1216x over previous
//
#include <hip/hip_runtime.h>
#include <math.h>

// Dims: N=2, T=2048, DM=1024, H=8, E=4, L=32, DK=DV=64
// Numerics: scan multiplier (1-sum_h G) ~ -1.4 => rec ~1e9, logits ~1e8
// (softmax==argmax). All GEMM-ish paths use split-bf16 (hi+lo, ~2^-17 eff).

typedef __attribute__((ext_vector_type(8))) short bf16x8;
typedef __attribute__((ext_vector_type(4))) float f32x4;

static __device__ __forceinline__ unsigned short f2bf(float f) {
  unsigned u = __float_as_uint(f);
  u += 0x7fffu + ((u >> 16) & 1u);   // RNE
  return (unsigned short)(u >> 16);
}
static __device__ __forceinline__ float bf2f(unsigned short h) {
  return __uint_as_float(((unsigned)h) << 16);
}
static __device__ __forceinline__ unsigned packbf(float f) {
  unsigned short h = f2bf(f);
  unsigned short l = f2bf(f - bf2f(h));
  return ((unsigned)h << 16) | (unsigned)l;
}
static __device__ __forceinline__ float unpackbf(unsigned u) {
  return __uint_as_float(u & 0xffff0000u) + __uint_as_float(u << 16);
}

#define GLDS(gp, lp) \
  __builtin_amdgcn_global_load_lds((const __attribute__((address_space(1))) void*)(gp), \
                                   (__attribute__((address_space(3))) void*)(lp), 16, 0, 0)

// ---------------- converts (f32 -> hi/lo bf16 planes) ----------------
__global__ __launch_bounds__(256) void cvt_X_split(const float* __restrict__ X,
                                                   unsigned short* __restrict__ Xh,
                                                   unsigned short* __restrict__ Xl) {
  const int i = (blockIdx.x * 256 + threadIdx.x) * 4;
  float4 v = *(const float4*)(X + i);
  ushort4 h, l;
  h.x = f2bf(v.x); l.x = f2bf(v.x - bf2f(h.x));
  h.y = f2bf(v.y); l.y = f2bf(v.y - bf2f(h.y));
  h.z = f2bf(v.z); l.z = f2bf(v.z - bf2f(h.z));
  h.w = f2bf(v.w); l.w = f2bf(v.w - bf2f(h.w));
  *(ushort4*)(Xh + i) = h;
  *(ushort4*)(Xl + i) = l;
}

__global__ __launch_bounds__(256) void cvt_W_split(const float* __restrict__ wK,
                                                   const float* __restrict__ wV,
                                                   const float* __restrict__ wQ,
                                                   const float* __restrict__ wG,
                                                   unsigned short* __restrict__ Wh,
                                                   unsigned short* __restrict__ Wl) {
  const int idx = (blockIdx.x * 256 + threadIdx.x) * 4;
  const int row = idx >> 10;
  const int col = idx & 1023;
  const float* src = nullptr;
  if (row < 512)       src = wK + (size_t)row * 1024;
  else if (row < 1024) src = wV + (size_t)(row - 512) * 1024;
  else if (row < 1536) src = wQ + (size_t)(row - 1024) * 1024;
  else if (row < 1568) src = wG + (size_t)(row - 1536) * 1024;
  float4 v = make_float4(0.f, 0.f, 0.f, 0.f);
  if (src) v = *(const float4*)(src + col);
  ushort4 h, l;
  h.x = f2bf(v.x); l.x = f2bf(v.x - bf2f(h.x));
  h.y = f2bf(v.y); l.y = f2bf(v.y - bf2f(h.y));
  h.z = f2bf(v.z); l.z = f2bf(v.z - bf2f(h.z));
  h.w = f2bf(v.w); l.w = f2bf(v.w - bf2f(h.w));
  *(ushort4*)(Wh + idx) = h;
  *(ushort4*)(Wl + idx) = l;
}

__global__ __launch_bounds__(256) void cvt_wOt_split(const float* __restrict__ wO,
                                                     unsigned short* __restrict__ wOth,
                                                     unsigned short* __restrict__ wOtl) {
  __shared__ float tile[32][33];
  const int tx = threadIdx.x;
  const int ty = threadIdx.y;
  const int n0 = blockIdx.x * 32;
  const int k0 = blockIdx.y * 32;
#pragma unroll
  for (int r = 0; r < 4; ++r)
    tile[ty * 4 + r][tx] = wO[(size_t)(k0 + ty * 4 + r) * 1024 + n0 + tx];
  __syncthreads();
#pragma unroll
  for (int r = 0; r < 4; ++r) {
    const float v = tile[tx][ty * 4 + r];
    const unsigned short h = f2bf(v);
    wOth[(size_t)(n0 + ty * 4 + r) * 512 + k0 + tx] = h;
    wOtl[(size_t)(n0 + ty * 4 + r) * 512 + k0 + tx] = f2bf(v - bf2f(h));
  }
}

// ---------------- K1: fused projection GEMM (split-bf16 MFMA, BK=64) --------
// C[r][c] = sum_k X[r][k]*W[c][k]; M=4096, Ncols=1664(pad), K=1024
__global__ __launch_bounds__(256) void gemm_proj(
    const unsigned short* __restrict__ Xh, const unsigned short* __restrict__ Xl,
    const unsigned short* __restrict__ Wh, const unsigned short* __restrict__ Wl,
    const float* __restrict__ bG,
    float* __restrict__ Kb, float* __restrict__ Vb, float* __restrict__ Qb,
    float* __restrict__ Gb)
{
  // two 32-k panels per buffer: [panel][row][32 shorts]
  __shared__ __align__(16) unsigned short Ash[2 * 128 * 32];
  __shared__ __align__(16) unsigned short Asl[2 * 128 * 32];
  __shared__ __align__(16) unsigned short Bsh[2 * 128 * 32];
  __shared__ __align__(16) unsigned short Bsl[2 * 128 * 32];
  const int tid  = threadIdx.x;
  const int lane = tid & 63;
  const int w    = tid >> 6;
  const int wr   = w >> 1, wc = w & 1;
  const int lm   = lane & 15, lq = lane >> 4;
  const int rb   = blockIdx.x * 128;
  const int cb   = blockIdx.y * 128;
  const int srow = lane >> 2;          // 0..15
  const int skc  = (lane & 3) * 8;     // 0,8,16,24

  f32x4 acc[4][4] = {};
  for (int k0 = 0; k0 < 1024; k0 += 64) {
#pragma unroll
    for (int p = 0; p < 2; ++p)
#pragma unroll
      for (int c = 0; c < 2; ++c) {
        const int r0   = w * 32 + c * 16;
        const int ldso = (p * 128 + r0) * 32;
        const size_t ga = (size_t)(rb + r0 + srow) * 1024 + k0 + p * 32 + skc;
        const size_t gb = (size_t)(cb + r0 + srow) * 1024 + k0 + p * 32 + skc;
        GLDS(Xh + ga, Ash + ldso);
        GLDS(Xl + ga, Asl + ldso);
        GLDS(Wh + gb, Bsh + ldso);
        GLDS(Wl + gb, Bsl + ldso);
      }
    __syncthreads();
#pragma unroll
    for (int ks = 0; ks < 2; ++ks) {
      bf16x8 ah[4], al[4], bh[4], bl[4];
#pragma unroll
      for (int i = 0; i < 4; ++i) {
        const int off = (ks * 128 + wr * 64 + i * 16 + lm) * 32 + lq * 8;
        ah[i] = *(const bf16x8*)(Ash + off);
        al[i] = *(const bf16x8*)(Asl + off);
      }
#pragma unroll
      for (int j = 0; j < 4; ++j) {
        const int off = (ks * 128 + wc * 64 + j * 16 + lm) * 32 + lq * 8;
        bh[j] = *(const bf16x8*)(Bsh + off);
        bl[j] = *(const bf16x8*)(Bsl + off);
      }
#pragma unroll
      for (int i = 0; i < 4; ++i)
#pragma unroll
        for (int j = 0; j < 4; ++j) {
          acc[i][j] = __builtin_amdgcn_mfma_f32_16x16x32_bf16(ah[i], bh[j], acc[i][j], 0, 0, 0);
          acc[i][j] = __builtin_amdgcn_mfma_f32_16x16x32_bf16(ah[i], bl[j], acc[i][j], 0, 0, 0);
          acc[i][j] = __builtin_amdgcn_mfma_f32_16x16x32_bf16(al[i], bh[j], acc[i][j], 0, 0, 0);
        }
    }
    __syncthreads();
  }
#pragma unroll
  for (int i = 0; i < 4; ++i) {
#pragma unroll
    for (int j = 0; j < 4; ++j) {
      const int c = cb + wc * 64 + j * 16 + lm;
      if (c >= 1568) continue;
#pragma unroll
      for (int rr = 0; rr < 4; ++rr) {
        const int m = rb + wr * 64 + i * 16 + lq * 4 + rr;
        const int n = m >> 11, t = m & 2047;
        const float v = acc[i][j][rr];
        if (c < 512) {
          Kb[(size_t)((n * 8 + (c >> 6)) * 2048 + t) * 64 + (c & 63)] = v;
        } else if (c < 1024) {
          const int cc = c - 512;
          Vb[(size_t)((n * 8 + (cc >> 6)) * 2048 + t) * 64 + (cc & 63)] = v;
        } else if (c < 1536) {
          const int cc = c - 1024;
          Qb[(size_t)((n * 8 + (cc >> 6)) * 2048 + t) * 64 + (cc & 63)] = v;
        } else {
          const int cc = c - 1536;  // h*4+e
          const float g = 1.0f / (1.0f + __expf(-(v + bG[cc])));
          Gb[(size_t)(n * 32 + cc) * 2048 + t] = g;
        }
      }
    }
  }
}

// ---------------- S1: gate + combine (fully parallel) ----------------
// A[n,e,t] = 1 - sum_h G; gK/gV[n,e,t,d] = sum_h G*K/V (packed bf16 hi/lo)
__global__ __launch_bounds__(256) void gate_combine(
    const float* __restrict__ Gb,   // (n, h*4+e, t)
    const float* __restrict__ Kb,   // (n,h,t,d)
    const float* __restrict__ Vb,
    float* __restrict__ Afac,       // (n,e,t)
    unsigned* __restrict__ gK,      // (n,e,t,d) packed
    unsigned* __restrict__ gV)
{
  const int d  = threadIdx.x & 63;
  const int e  = threadIdx.x >> 6;
  const int n  = blockIdx.x >> 8;
  const int t0 = (blockIdx.x & 255) * 8;
#pragma unroll
  for (int tt = 0; tt < 8; ++tt) {
    const int t = t0 + tt;
    float gk = 0.f, gv = 0.f, gs = 0.f;
#pragma unroll
    for (int h = 0; h < 8; ++h) {
      const float g = Gb[((size_t)(n * 32) + h * 4 + e) * 2048 + t];
      gs += g;
      gk = fmaf(g, Kb[(size_t)((n * 8 + h) * 2048 + t) * 64 + d], gk);
      gv = fmaf(g, Vb[(size_t)((n * 8 + h) * 2048 + t) * 64 + d], gv);
    }
    const size_t o = (size_t)((n * 4 + e) * 2048 + t) * 64 + d;
    gK[o] = packbf(gk);
    gV[o] = packbf(gv);
    if (d == 0) Afac[(size_t)(n * 4 + e) * 2048 + t] = 1.0f - gs;
  }
}

// ---------------- S2: lag-32 linear scan (streaming, prefetched) -----------
// y_j = a_j*y_{j-1} + b_j per chain (n,e,i,d), j = 0..63
__global__ __launch_bounds__(64) void scan2(
    const float* __restrict__ Afac,   // (n,e,t)
    const unsigned* __restrict__ gK,  // (n,e,t,d) packed
    const unsigned* __restrict__ gV,
    const float* __restrict__ initK,  // (E,32,64)
    const float* __restrict__ initV,
    unsigned* __restrict__ recK,      // (n,e,2080,64) packed
    unsigned* __restrict__ recV)
{
  const int d  = threadIdx.x;
  const int ne = blockIdx.x;   // 0..7
  const int i  = blockIdx.y;   // 0..31
  const int e  = ne & 3;
  const bool isV = (blockIdx.z != 0);
  const unsigned* src = (isV ? gV : gK) + ((size_t)ne * 2048 + i) * 64 + d;
  const float*   init = isV ? initV : initK;
  unsigned*       rec = isV ? recV : recK;

  float y = init[(size_t)(e * 32 + i) * 64 + d];
  rec[(size_t)(ne * 2080 + i) * 64 + d] = packbf(y);
  const float* Arow = Afac + (size_t)ne * 2048 + i;
  unsigned* dst = rec + ((size_t)ne * 2080 + 32 + i) * 64 + d;

  unsigned u0[8];
  float    a0[8];
#pragma unroll
  for (int k = 0; k < 8; ++k) {
    a0[k] = Arow[k * 32];
    u0[k] = src[(size_t)k * 2048];
  }
  for (int J = 0; J < 64; J += 8) {
    unsigned u1[8];
    float    a1[8];
    if (J + 8 < 64) {
#pragma unroll
      for (int k = 0; k < 8; ++k) {
        a1[k] = Arow[(J + 8 + k) * 32];
        u1[k] = src[(size_t)(J + 8 + k) * 2048];
      }
    }
#pragma unroll
    for (int k = 0; k < 8; ++k) {
      y = fmaf(a0[k], y, unpackbf(u0[k]));
      dst[(size_t)(J + k) * 2048] = packbf(y);
    }
#pragma unroll
    for (int k = 0; k < 8; ++k) { a0[k] = a1[k]; u0[k] = u1[k]; }
  }
}

// ---------------- K3: banded MFMA attention ----------------
#define TB 16
__global__ __launch_bounds__(512) void attn_kernel(
    const float* __restrict__ Qb,       // (n,h,t,64) f32
    const unsigned* __restrict__ recK,  // (n,e,2080,64) packed
    const unsigned* __restrict__ recV,
    unsigned short* __restrict__ Ybh,   // (n*T,512) hi
    unsigned short* __restrict__ Ybl)   // lo
{
  __shared__ __align__(16) unsigned short lds[32512];
  const int KS_HI = 0;            // 48*72 = 3456
  const int KS_LO = 3456;
  const int VT_HI = 6912;         // 64*56 = 3584
  const int VT_LO = 10496;
  const int PW0   = 14080;        // 8 waves * 16*72 per plane

  const int tid  = threadIdx.x;
  const int lane = tid & 63;
  const int w    = tid >> 6;           // head
  const int lm   = lane & 15, lq = lane >> 4;
  const int n    = blockIdx.x >> 7;
  const int t0   = (blockIdx.x & 127) * TB;
  const int maxidx = (2078 - t0) * 64 + 63;

  bf16x8 aqh[2], aql[2];
  {
    const float* qrow = Qb + ((size_t)(n * 8 + w) * 2048 + t0 + lm) * 64 + lq * 8;
#pragma unroll
    for (int ks = 0; ks < 2; ++ks) {
      float4 q0 = *(const float4*)(qrow + ks * 32);
      float4 q1 = *(const float4*)(qrow + ks * 32 + 4);
      float qv[8] = {q0.x, q0.y, q0.z, q0.w, q1.x, q1.y, q1.z, q1.w};
#pragma unroll
      for (int j = 0; j < 8; ++j) {
        unsigned short h = f2bf(qv[j]);
        aqh[ks][j] = (short)h;
        aql[ks][j] = (short)f2bf(qv[j] - bf2f(h));
      }
    }
  }

  f32x4 S[4][3];
  for (int e = 0; e < 4; ++e) {
    __syncthreads();
    {
      const unsigned* src = recK + ((size_t)(n * 4 + e) * 2080 + t0 + 1) * 64;
#pragma unroll
      for (int p = 0; p < 6; ++p) {
        const int idx = tid + p * 512;
        const int sl = idx >> 6, d = idx & 63;
        const unsigned u = src[idx <= maxidx ? idx : maxidx];
        lds[KS_HI + sl * 72 + d] = (unsigned short)(u >> 16);
        lds[KS_LO + sl * 72 + d] = (unsigned short)(u & 0xffffu);
      }
    }
    __syncthreads();
#pragma unroll
    for (int j = 0; j < 3; ++j) {
      f32x4 s = {0.f, 0.f, 0.f, 0.f};
#pragma unroll
      for (int ks = 0; ks < 2; ++ks) {
        const int boff = (j * 16 + lm) * 72 + ks * 32 + lq * 8;
        bf16x8 bh = *(const bf16x8*)(lds + KS_HI + boff);
        bf16x8 bl = *(const bf16x8*)(lds + KS_LO + boff);
        s = __builtin_amdgcn_mfma_f32_16x16x32_bf16(aqh[ks], bh, s, 0, 0, 0);
        s = __builtin_amdgcn_mfma_f32_16x16x32_bf16(aqh[ks], bl, s, 0, 0, 0);
        s = __builtin_amdgcn_mfma_f32_16x16x32_bf16(aql[ks], bh, s, 0, 0, 0);
      }
      S[e][j] = s;
    }
  }

  const float NEG = -3.0e38f;
  float mx[4] = {NEG, NEG, NEG, NEG};
#pragma unroll
  for (int e = 0; e < 4; ++e)
#pragma unroll
    for (int j = 0; j < 3; ++j) {
      const int sl = j * 16 + lm;
#pragma unroll
      for (int rr = 0; rr < 4; ++rr) {
        const int m = lq * 4 + rr;
        const bool valid = ((unsigned)(sl - m) <= 31u);
        const float v = valid ? S[e][j][rr] * 0.125f : NEG;
        S[e][j][rr] = v;
        mx[rr] = fmaxf(mx[rr], v);
      }
    }
#pragma unroll
  for (int rr = 0; rr < 4; ++rr) {
    float m = mx[rr];
    m = fmaxf(m, __shfl_xor(m, 1));
    m = fmaxf(m, __shfl_xor(m, 2));
    m = fmaxf(m, __shfl_xor(m, 4));
    m = fmaxf(m, __shfl_xor(m, 8));
    mx[rr] = m;
  }
  float sm[4] = {0.f, 0.f, 0.f, 0.f};
#pragma unroll
  for (int e = 0; e < 4; ++e)
#pragma unroll
    for (int j = 0; j < 3; ++j)
#pragma unroll
      for (int rr = 0; rr < 4; ++rr) {
        const float p = __expf(S[e][j][rr] - mx[rr]);
        S[e][j][rr] = p;
        sm[rr] += p;
      }
  float inv[4];
#pragma unroll
  for (int rr = 0; rr < 4; ++rr) {
    float s = sm[rr];
    s += __shfl_xor(s, 1);
    s += __shfl_xor(s, 2);
    s += __shfl_xor(s, 4);
    s += __shfl_xor(s, 8);
    inv[rr] = 1.0f / s;
  }

  const int PWH = PW0 + w * 1152;
  const int PWL = PW0 + 9216 + w * 1152;
  {
    const int r = lane >> 2, c0 = 48 + (lane & 3) * 4;
#pragma unroll
    for (int c = 0; c < 4; ++c) {
      lds[PWH + r * 72 + c0 + c] = 0;
      lds[PWL + r * 72 + c0 + c] = 0;
    }
  }
  f32x4 O[4] = {};
  for (int e = 0; e < 4; ++e) {
    __syncthreads();
    {
      const unsigned* src = recV + ((size_t)(n * 4 + e) * 2080 + t0 + 1) * 64;
#pragma unroll
      for (int p = 0; p < 6; ++p) {
        const int idx = tid + p * 512;
        const int sl = idx >> 6, d = idx & 63;
        const unsigned u = src[idx <= maxidx ? idx : maxidx];
        lds[VT_HI + d * 56 + sl] = (unsigned short)(u >> 16);
        lds[VT_LO + d * 56 + sl] = (unsigned short)(u & 0xffffu);
      }
    }
#pragma unroll
    for (int j = 0; j < 3; ++j)
#pragma unroll
      for (int rr = 0; rr < 4; ++rr) {
        const float p = S[e][j][rr] * inv[rr];
        const unsigned short h = f2bf(p);
        lds[PWH + (lq * 4 + rr) * 72 + j * 16 + lm] = h;
        lds[PWL + (lq * 4 + rr) * 72 + j * 16 + lm] = f2bf(p - bf2f(h));
      }
    __syncthreads();
    bf16x8 ah[2], al[2];
#pragma unroll
    for (int ks = 0; ks < 2; ++ks) {
      ah[ks] = *(const bf16x8*)(lds + PWH + lm * 72 + ks * 32 + lq * 8);
      al[ks] = *(const bf16x8*)(lds + PWL + lm * 72 + ks * 32 + lq * 8);
    }
#pragma unroll
    for (int nt = 0; nt < 4; ++nt)
#pragma unroll
      for (int ks = 0; ks < 2; ++ks) {
        const int boff = (nt * 16 + lm) * 56 + ks * 32 + lq * 8;
        bf16x8 vh = *(const bf16x8*)(lds + VT_HI + boff);
        bf16x8 vl = *(const bf16x8*)(lds + VT_LO + boff);
        O[nt] = __builtin_amdgcn_mfma_f32_16x16x32_bf16(ah[ks], vh, O[nt], 0, 0, 0);
        O[nt] = __builtin_amdgcn_mfma_f32_16x16x32_bf16(ah[ks], vl, O[nt], 0, 0, 0);
        O[nt] = __builtin_amdgcn_mfma_f32_16x16x32_bf16(al[ks], vh, O[nt], 0, 0, 0);
      }
  }

#pragma unroll
  for (int nt = 0; nt < 4; ++nt)
#pragma unroll
    for (int rr = 0; rr < 4; ++rr) {
      const int t = t0 + lq * 4 + rr;
      const size_t oi = ((size_t)(n * 2048 + t)) * 512 + w * 64 + nt * 16 + lm;
      const float v = O[nt][rr];
      const unsigned short h = f2bf(v);
      Ybh[oi] = h;
      Ybl[oi] = f2bf(v - bf2f(h));
    }
}

// ---------------- K4: output GEMM (split-bf16 MFMA, BK=64) ----------------
__global__ __launch_bounds__(256) void gemm_out(
    const unsigned short* __restrict__ Yh, const unsigned short* __restrict__ Yl,
    const unsigned short* __restrict__ Wh, const unsigned short* __restrict__ Wl,
    float* __restrict__ out)
{
  __shared__ __align__(16) unsigned short Ash[2 * 128 * 32];
  __shared__ __align__(16) unsigned short Asl[2 * 128 * 32];
  __shared__ __align__(16) unsigned short Bsh[2 * 128 * 32];
  __shared__ __align__(16) unsigned short Bsl[2 * 128 * 32];
  const int tid  = threadIdx.x;
  const int lane = tid & 63;
  const int w    = tid >> 6;
  const int wr   = w >> 1, wc = w & 1;
  const int lm   = lane & 15, lq = lane >> 4;
  const int rb   = blockIdx.x * 128;
  const int cb   = blockIdx.y * 128;
  const int srow = lane >> 2;
  const int skc  = (lane & 3) * 8;

  f32x4 acc[4][4] = {};
  for (int k0 = 0; k0 < 512; k0 += 64) {
#pragma unroll
    for (int p = 0; p < 2; ++p)
#pragma unroll
      for (int c = 0; c < 2; ++c) {
        const int r0   = w * 32 + c * 16;
        const int ldso = (p * 128 + r0) * 32;
        const size_t ga = (size_t)(rb + r0 + srow) * 512 + k0 + p * 32 + skc;
        const size_t gb = (size_t)(cb + r0 + srow) * 512 + k0 + p * 32 + skc;
        GLDS(Yh + ga, Ash + ldso);
        GLDS(Yl + ga, Asl + ldso);
        GLDS(Wh + gb, Bsh + ldso);
        GLDS(Wl + gb, Bsl + ldso);
      }
    __syncthreads();
#pragma unroll
    for (int ks = 0; ks < 2; ++ks) {
      bf16x8 ah[4], al[4], bh[4], bl[4];
#pragma unroll
      for (int i = 0; i < 4; ++i) {
        const int off = (ks * 128 + wr * 64 + i * 16 + lm) * 32 + lq * 8;
        ah[i] = *(const bf16x8*)(Ash + off);
        al[i] = *(const bf16x8*)(Asl + off);
      }
#pragma unroll
      for (int j = 0; j < 4; ++j) {
        const int off = (ks * 128 + wc * 64 + j * 16 + lm) * 32 + lq * 8;
        bh[j] = *(const bf16x8*)(Bsh + off);
        bl[j] = *(const bf16x8*)(Bsl + off);
      }
#pragma unroll
      for (int i = 0; i < 4; ++i)
#pragma unroll
        for (int j = 0; j < 4; ++j) {
          acc[i][j] = __builtin_amdgcn_mfma_f32_16x16x32_bf16(ah[i], bh[j], acc[i][j], 0, 0, 0);
          acc[i][j] = __builtin_amdgcn_mfma_f32_16x16x32_bf16(ah[i], bl[j], acc[i][j], 0, 0, 0);
          acc[i][j] = __builtin_amdgcn_mfma_f32_16x16x32_bf16(al[i], bh[j], acc[i][j], 0, 0, 0);
        }
    }
    __syncthreads();
  }
#pragma unroll
  for (int i = 0; i < 4; ++i)
#pragma unroll
    for (int j = 0; j < 4; ++j)
#pragma unroll
      for (int rr = 0; rr < 4; ++rr) {
        const int m = rb + wr * 64 + i * 16 + lq * 4 + rr;
        const int c = cb + wc * 64 + j * 16 + lm;
        out[(size_t)m * 1024 + c] = acc[i][j][rr];
      }
}

extern "C" void kernel_launch(void* const* d_in, const int* in_sizes, int n_in,
                              void* d_out, int out_size, void* d_ws, size_t ws_size,
                              hipStream_t stream) {
  const float* X     = (const float*)d_in[0];
  const float* wG    = (const float*)d_in[1];
  const float* bG    = (const float*)d_in[2];
  const float* wK    = (const float*)d_in[3];
  const float* wV    = (const float*)d_in[4];
  const float* wQ    = (const float*)d_in[5];
  const float* wO    = (const float*)d_in[6];
  const float* initK = (const float*)d_in[7];
  const float* initV = (const float*)d_in[8];
  float* out = (float*)d_out;

  // --- workspace layout (51.4 MB, heavy lifetime aliasing) ---
  float* ws = (float*)d_ws;
  float* Kb = ws;                    // 2,097,152 f
  float* Vb = Kb + 2097152;          // 2,097,152 f
  float* Qb = Vb + 2097152;          // 2,097,152 f
  float* Gb = Qb + 2097152;          //   131,072 f
  unsigned short* Xh   = (unsigned short*)(Gb + 131072);  // 4,194,304 s
  unsigned short* Xl   = Xh + 4194304;                    // 4,194,304 s
  unsigned short* Wh   = Xl + 4194304;                    // 1,703,936 s
  unsigned short* Wl   = Wh + 1703936;                    // 1,703,936 s
  unsigned short* wOth = Wl + 1703936;                    //   524,288 s
  unsigned short* wOtl = wOth + 524288;                   //   524,288 s
  // aliases (lifetimes don't overlap):
  unsigned* P    = (unsigned*)Xh;       // X planes dead after gemm_proj
  unsigned* recK = P;                   // 1,064,960 u
  unsigned* recV = P + 1064960;         // 1,064,960 u
  unsigned* gK   = P + 2129920;         // 1,048,576 u (ends 12.7MB < 16.8MB region)
  unsigned* gV   = (unsigned*)Wh;       // 1,048,576 u (W planes dead after gemm_proj)
  float*   Afac  = (float*)(gV + 1048576);  // 16,384 f (still inside Wh+Wl)
  unsigned short* Ybh = (unsigned short*)Kb;  // Kb dead after gate_combine
  unsigned short* Ybl = Ybh + 2097152;

  cvt_X_split<<<dim3(4096), dim3(256), 0, stream>>>(X, Xh, Xl);
  cvt_W_split<<<dim3(1664), dim3(256), 0, stream>>>(wK, wV, wQ, wG, Wh, Wl);
  cvt_wOt_split<<<dim3(32, 16), dim3(32, 8), 0, stream>>>(wO, wOth, wOtl);
  gemm_proj<<<dim3(32, 13), dim3(256), 0, stream>>>(Xh, Xl, Wh, Wl, bG, Kb, Vb, Qb, Gb);
  gate_combine<<<dim3(512), dim3(256), 0, stream>>>(Gb, Kb, Vb, Afac, gK, gV);
  scan2<<<dim3(8, 32, 2), dim3(64), 0, stream>>>(Afac, gK, gV, initK, initV, recK, recV);
  attn_kernel<<<dim3(256), dim3(512), 0, stream>>>(Qb, recK, recV, Ybh, Ybl);
  gemm_out<<<dim3(32, 8), dim3(256), 0, stream>>>(Ybh, Ybl, wOth, wOtl, out);
}

// Round 7
// 193.175 us; speedup vs baseline: 3.0929x; 1.0276x over previous
//
#include <hip/hip_runtime.h>
#include <math.h>

// Dims: N=2, T=2048, DM=1024, H=8, E=4, L=32, DK=DV=64
// Numerics: scan multiplier (1-sum_h G) ~ -1.4 => rec ~1e9, logits ~1e8
// (softmax==argmax). GEMM paths use split-bf16 (hi+lo, ~2^-17 eff). Output is
// bf16 => error floor = 1 ULP of max ~ 8.4e6; post-softmax V can be bf16-only.

typedef __attribute__((ext_vector_type(8))) short bf16x8;
typedef __attribute__((ext_vector_type(4))) float f32x4;

static __device__ __forceinline__ unsigned short f2bf(float f) {
  unsigned u = __float_as_uint(f);
  u += 0x7fffu + ((u >> 16) & 1u);   // RNE
  return (unsigned short)(u >> 16);
}
static __device__ __forceinline__ float bf2f(unsigned short h) {
  return __uint_as_float(((unsigned)h) << 16);
}
static __device__ __forceinline__ unsigned packbf(float f) {
  unsigned short h = f2bf(f);
  unsigned short l = f2bf(f - bf2f(h));
  return ((unsigned)h << 16) | (unsigned)l;
}
static __device__ __forceinline__ float unpackbf(unsigned u) {
  return __uint_as_float(u & 0xffff0000u) + __uint_as_float(u << 16);
}

#define GLDS(gp, lp) \
  __builtin_amdgcn_global_load_lds((const __attribute__((address_space(1))) void*)(gp), \
                                   (__attribute__((address_space(3))) void*)(lp), 16, 0, 0)

// ---------------- converts (f32 -> hi/lo bf16 planes), X+W fused -----------
__global__ __launch_bounds__(256) void cvt_XW(
    const float* __restrict__ X,
    const float* __restrict__ wK, const float* __restrict__ wV,
    const float* __restrict__ wQ, const float* __restrict__ wG,
    unsigned short* __restrict__ Xh, unsigned short* __restrict__ Xl,
    unsigned short* __restrict__ Wh, unsigned short* __restrict__ Wl)
{
  const int g = blockIdx.x * 256 + threadIdx.x;
  const float* src;
  unsigned short *dh, *dl;
  int idx;
  if (g < 1048576) {              // X: 4,194,304 floats
    idx = g * 4;
    src = X + idx;
    dh = Xh + idx; dl = Xl + idx;
  } else {                        // W: 1664 rows x 1024
    idx = (g - 1048576) * 4;
    const int row = idx >> 10;
    const int col = idx & 1023;
    const float* s = nullptr;
    if (row < 512)       s = wK + (size_t)row * 1024;
    else if (row < 1024) s = wV + (size_t)(row - 512) * 1024;
    else if (row < 1536) s = wQ + (size_t)(row - 1024) * 1024;
    else if (row < 1568) s = wG + (size_t)(row - 1536) * 1024;
    src = s ? s + col : nullptr;
    dh = Wh + idx; dl = Wl + idx;
  }
  float4 v = make_float4(0.f, 0.f, 0.f, 0.f);
  if (src) v = *(const float4*)src;
  ushort4 h, l;
  h.x = f2bf(v.x); l.x = f2bf(v.x - bf2f(h.x));
  h.y = f2bf(v.y); l.y = f2bf(v.y - bf2f(h.y));
  h.z = f2bf(v.z); l.z = f2bf(v.z - bf2f(h.z));
  h.w = f2bf(v.w); l.w = f2bf(v.w - bf2f(h.w));
  *(ushort4*)dh = h;
  *(ushort4*)dl = l;
}

__global__ __launch_bounds__(256) void cvt_wOt_split(const float* __restrict__ wO,
                                                     unsigned short* __restrict__ wOth,
                                                     unsigned short* __restrict__ wOtl) {
  __shared__ float tile[32][33];
  const int tx = threadIdx.x;
  const int ty = threadIdx.y;
  const int n0 = blockIdx.x * 32;
  const int k0 = blockIdx.y * 32;
#pragma unroll
  for (int r = 0; r < 4; ++r)
    tile[ty * 4 + r][tx] = wO[(size_t)(k0 + ty * 4 + r) * 1024 + n0 + tx];
  __syncthreads();
#pragma unroll
  for (int r = 0; r < 4; ++r) {
    const float v = tile[tx][ty * 4 + r];
    const unsigned short h = f2bf(v);
    wOth[(size_t)(n0 + ty * 4 + r) * 512 + k0 + tx] = h;
    wOtl[(size_t)(n0 + ty * 4 + r) * 512 + k0 + tx] = f2bf(v - bf2f(h));
  }
}

// ---------------- K1: fused projection GEMM (split-bf16 MFMA, BK=64) --------
__global__ __launch_bounds__(256) void gemm_proj(
    const unsigned short* __restrict__ Xh, const unsigned short* __restrict__ Xl,
    const unsigned short* __restrict__ Wh, const unsigned short* __restrict__ Wl,
    const float* __restrict__ bG,
    float* __restrict__ Kb, float* __restrict__ Vb, float* __restrict__ Qb,
    float* __restrict__ Gb)
{
  __shared__ __align__(16) unsigned short Ash[2 * 128 * 32];
  __shared__ __align__(16) unsigned short Asl[2 * 128 * 32];
  __shared__ __align__(16) unsigned short Bsh[2 * 128 * 32];
  __shared__ __align__(16) unsigned short Bsl[2 * 128 * 32];
  const int tid  = threadIdx.x;
  const int lane = tid & 63;
  const int w    = tid >> 6;
  const int wr   = w >> 1, wc = w & 1;
  const int lm   = lane & 15, lq = lane >> 4;
  const int rb   = blockIdx.x * 128;
  const int cb   = blockIdx.y * 128;
  const int srow = lane >> 2;
  const int skc  = (lane & 3) * 8;

  f32x4 acc[4][4] = {};
  for (int k0 = 0; k0 < 1024; k0 += 64) {
#pragma unroll
    for (int p = 0; p < 2; ++p)
#pragma unroll
      for (int c = 0; c < 2; ++c) {
        const int r0   = w * 32 + c * 16;
        const int ldso = (p * 128 + r0) * 32;
        const size_t ga = (size_t)(rb + r0 + srow) * 1024 + k0 + p * 32 + skc;
        const size_t gb = (size_t)(cb + r0 + srow) * 1024 + k0 + p * 32 + skc;
        GLDS(Xh + ga, Ash + ldso);
        GLDS(Xl + ga, Asl + ldso);
        GLDS(Wh + gb, Bsh + ldso);
        GLDS(Wl + gb, Bsl + ldso);
      }
    __syncthreads();
#pragma unroll
    for (int ks = 0; ks < 2; ++ks) {
      bf16x8 ah[4], al[4], bh[4], bl[4];
#pragma unroll
      for (int i = 0; i < 4; ++i) {
        const int off = (ks * 128 + wr * 64 + i * 16 + lm) * 32 + lq * 8;
        ah[i] = *(const bf16x8*)(Ash + off);
        al[i] = *(const bf16x8*)(Asl + off);
      }
#pragma unroll
      for (int j = 0; j < 4; ++j) {
        const int off = (ks * 128 + wc * 64 + j * 16 + lm) * 32 + lq * 8;
        bh[j] = *(const bf16x8*)(Bsh + off);
        bl[j] = *(const bf16x8*)(Bsl + off);
      }
#pragma unroll
      for (int i = 0; i < 4; ++i)
#pragma unroll
        for (int j = 0; j < 4; ++j) {
          acc[i][j] = __builtin_amdgcn_mfma_f32_16x16x32_bf16(ah[i], bh[j], acc[i][j], 0, 0, 0);
          acc[i][j] = __builtin_amdgcn_mfma_f32_16x16x32_bf16(ah[i], bl[j], acc[i][j], 0, 0, 0);
          acc[i][j] = __builtin_amdgcn_mfma_f32_16x16x32_bf16(al[i], bh[j], acc[i][j], 0, 0, 0);
        }
    }
    __syncthreads();
  }
#pragma unroll
  for (int i = 0; i < 4; ++i) {
#pragma unroll
    for (int j = 0; j < 4; ++j) {
      const int c = cb + wc * 64 + j * 16 + lm;
      if (c >= 1568) continue;
#pragma unroll
      for (int rr = 0; rr < 4; ++rr) {
        const int m = rb + wr * 64 + i * 16 + lq * 4 + rr;
        const int n = m >> 11, t = m & 2047;
        const float v = acc[i][j][rr];
        if (c < 512) {
          Kb[(size_t)((n * 8 + (c >> 6)) * 2048 + t) * 64 + (c & 63)] = v;
        } else if (c < 1024) {
          const int cc = c - 512;
          Vb[(size_t)((n * 8 + (cc >> 6)) * 2048 + t) * 64 + (cc & 63)] = v;
        } else if (c < 1536) {
          const int cc = c - 1024;
          Qb[(size_t)((n * 8 + (cc >> 6)) * 2048 + t) * 64 + (cc & 63)] = v;
        } else {
          const int cc = c - 1536;  // h*4+e
          const float g = 1.0f / (1.0f + __expf(-(v + bG[cc])));
          Gb[(size_t)(n * 32 + cc) * 2048 + t] = g;
        }
      }
    }
  }
}

// ---------------- S1: gate + combine (e-inner; K/V read once) ----------------
__global__ __launch_bounds__(256) void gate_combine(
    const float* __restrict__ Gb,   // (n, h*4+e, t)
    const float* __restrict__ Kb,   // (n,h,t,d)
    const float* __restrict__ Vb,
    float* __restrict__ Afac,       // (n,e,t)
    unsigned* __restrict__ gK,      // (n,e,t,d) packed
    unsigned* __restrict__ gV)
{
  __shared__ float Gs[16][32];      // [tl][h*4+e]
  const int tid = threadIdx.x;
  const int n   = blockIdx.x >> 7;
  const int t0  = (blockIdx.x & 127) * 16;
  for (int idx = tid; idx < 512; idx += 256) {
    const int he = idx & 31, tl = idx >> 5;
    Gs[tl][he] = Gb[((size_t)n * 32 + he) * 2048 + t0 + tl];
  }
  __syncthreads();
  const int d  = tid & 63;
  const int ts = tid >> 6;          // 0..3
#pragma unroll
  for (int tt = 0; tt < 4; ++tt) {
    const int tl = ts * 4 + tt;
    const int t  = t0 + tl;
    float ak[4] = {}, av[4] = {};
#pragma unroll
    for (int h = 0; h < 8; ++h) {
      const float kk = Kb[(size_t)((n * 8 + h) * 2048 + t) * 64 + d];
      const float vv = Vb[(size_t)((n * 8 + h) * 2048 + t) * 64 + d];
#pragma unroll
      for (int e = 0; e < 4; ++e) {
        const float g = Gs[tl][h * 4 + e];
        ak[e] = fmaf(g, kk, ak[e]);
        av[e] = fmaf(g, vv, av[e]);
      }
    }
#pragma unroll
    for (int e = 0; e < 4; ++e) {
      const size_t o = (size_t)((n * 4 + e) * 2048 + t) * 64 + d;
      gK[o] = packbf(ak[e]);
      gV[o] = packbf(av[e]);
    }
  }
  if (tid < 64) {
    const int e = tid & 3, tl = tid >> 2;
    float gs = 0.f;
#pragma unroll
    for (int h = 0; h < 8; ++h) gs += Gs[tl][h * 4 + e];
    Afac[(size_t)(n * 4 + e) * 2048 + t0 + tl] = 1.0f - gs;
  }
}

// ---------------- S2: lag-32 linear scan (streaming, prefetched) -----------
__global__ __launch_bounds__(64) void scan2(
    const float* __restrict__ Afac,   // (n,e,t)
    const unsigned* __restrict__ gK,  // (n,e,t,d) packed
    const unsigned* __restrict__ gV,
    const float* __restrict__ initK,  // (E,32,64)
    const float* __restrict__ initV,
    unsigned* __restrict__ recK,      // (n,e,2080,64) packed
    unsigned* __restrict__ recV)
{
  const int d  = threadIdx.x;
  const int ne = blockIdx.x;
  const int i  = blockIdx.y;
  const int e  = ne & 3;
  const bool isV = (blockIdx.z != 0);
  const unsigned* src = (isV ? gV : gK) + ((size_t)ne * 2048 + i) * 64 + d;
  const float*   init = isV ? initV : initK;
  unsigned*       rec = isV ? recV : recK;

  float y = init[(size_t)(e * 32 + i) * 64 + d];
  rec[(size_t)(ne * 2080 + i) * 64 + d] = packbf(y);
  const float* Arow = Afac + (size_t)ne * 2048 + i;
  unsigned* dst = rec + ((size_t)ne * 2080 + 32 + i) * 64 + d;

  unsigned u0[8];
  float    a0[8];
#pragma unroll
  for (int k = 0; k < 8; ++k) {
    a0[k] = Arow[k * 32];
    u0[k] = src[(size_t)k * 2048];
  }
  for (int J = 0; J < 64; J += 8) {
    unsigned u1[8];
    float    a1[8];
    if (J + 8 < 64) {
#pragma unroll
      for (int k = 0; k < 8; ++k) {
        a1[k] = Arow[(J + 8 + k) * 32];
        u1[k] = src[(size_t)(J + 8 + k) * 2048];
      }
    }
#pragma unroll
    for (int k = 0; k < 8; ++k) {
      y = fmaf(a0[k], y, unpackbf(u0[k]));
      dst[(size_t)(J + k) * 2048] = packbf(y);
    }
#pragma unroll
    for (int k = 0; k < 8; ++k) { a0[k] = a1[k]; u0[k] = u1[k]; }
  }
}

// ---------------- K3: banded MFMA attention (single-barrier, in-bounds) -----
// Block: (n, 16 t-rows), 512 thr = 8 waves (wave=head).
// LDS (shorts): Ks hi/lo 4e x [48 s][72], Vt hi 4e x [64 d][80] (cols 48..63
// zeroed, 64..79 never read), per-wave P hi/lo [16][72] (cols 48..63 zeroed).
// Total 66,560 shorts = 133,120 B. All MFMA fragment reads in-bounds:
// Ks max 3447<3456, Vt max 5103<5120, P max 1143<1152.
#define TB 16
#define KS_SZ 3456            // 48*72 per e per plane
#define KS_LO 13824           // 4*KS_SZ
#define VT_B  27648
#define VT_SZ 5120            // 64*80 per e (hi only)
#define P_B   48128           // VT_B + 4*VT_SZ
__global__ __launch_bounds__(512) void attn_kernel(
    const float* __restrict__ Qb,       // (n,h,t,64) f32
    const unsigned* __restrict__ recK,  // (n,e,2080,64) packed
    const unsigned* __restrict__ recV,
    unsigned short* __restrict__ Ybh,   // (n*T,512) hi
    unsigned short* __restrict__ Ybl)   // lo
{
  __shared__ __align__(16) unsigned short lds[66560];
  const int tid  = threadIdx.x;
  const int lane = tid & 63;
  const int w    = tid >> 6;           // head
  const int lm   = lane & 15, lq = lane >> 4;
  const int n    = blockIdx.x >> 7;
  const int t0   = (blockIdx.x & 127) * TB;
  const int maxidx = (2078 - t0) * 64 + 63;   // clamp reads to s<=2079

  // Q A-frags (hi/lo x 2 ksteps) straight from global
  bf16x8 aqh[2], aql[2];
  {
    const float* qrow = Qb + ((size_t)(n * 8 + w) * 2048 + t0 + lm) * 64 + lq * 8;
#pragma unroll
    for (int ks = 0; ks < 2; ++ks) {
      float4 q0 = *(const float4*)(qrow + ks * 32);
      float4 q1 = *(const float4*)(qrow + ks * 32 + 4);
      float qv[8] = {q0.x, q0.y, q0.z, q0.w, q1.x, q1.y, q1.z, q1.w};
#pragma unroll
      for (int j = 0; j < 8; ++j) {
        unsigned short h = f2bf(qv[j]);
        aqh[ks][j] = (short)h;
        aql[ks][j] = (short)f2bf(qv[j] - bf2f(h));
      }
    }
  }

  // ---- stage K hi/lo + V^T hi for all 4 experts ----
#pragma unroll
  for (int e = 0; e < 4; ++e) {
    const unsigned* sK = recK + ((size_t)(n * 4 + e) * 2080 + t0 + 1) * 64;
    const unsigned* sV = recV + ((size_t)(n * 4 + e) * 2080 + t0 + 1) * 64;
#pragma unroll
    for (int p = 0; p < 6; ++p) {
      const int idx = tid + p * 512;
      const int ci  = idx <= maxidx ? idx : maxidx;
      const int sl  = idx >> 6, d = idx & 63;
      const unsigned uk = sK[ci];
      const unsigned uv = sV[ci];
      lds[e * KS_SZ + sl * 72 + d]         = (unsigned short)(uk >> 16);
      lds[KS_LO + e * KS_SZ + sl * 72 + d] = (unsigned short)(uk & 0xffffu);
      lds[VT_B + e * VT_SZ + d * 80 + sl]  = (unsigned short)(uv >> 16);
    }
  }
  // zero Vt pad cols 48..63 (read by PV kstep1 with A=0 there; must be finite)
  for (int idx = tid; idx < 2048; idx += 512) {   // dword writes
    const int e = idx >> 9, r = idx & 511;
    const int d = r >> 3, c = r & 7;
    *(unsigned*)(lds + VT_B + e * VT_SZ + d * 80 + 48 + c * 2) = 0u;
  }
  // zero this wave's P pad cols 48..63 (own region, no barrier needed)
  const int PWH = P_B + w * 2304;
  const int PWL = PWH + 1152;
  {
    const int r = lane >> 2, c0 = 48 + (lane & 3) * 4;
#pragma unroll
    for (int c = 0; c < 4; ++c) {
      lds[PWH + r * 72 + c0 + c] = 0;
      lds[PWL + r * 72 + c0 + c] = 0;
    }
  }
  __syncthreads();   // the ONLY block barrier

  // ---- Phase A: scores ----
  f32x4 S[4][3];
#pragma unroll
  for (int e = 0; e < 4; ++e)
#pragma unroll
    for (int j = 0; j < 3; ++j) {
      f32x4 s = {0.f, 0.f, 0.f, 0.f};
#pragma unroll
      for (int ks = 0; ks < 2; ++ks) {
        const int boff = (j * 16 + lm) * 72 + ks * 32 + lq * 8;
        bf16x8 bh = *(const bf16x8*)(lds + e * KS_SZ + boff);
        bf16x8 bl = *(const bf16x8*)(lds + KS_LO + e * KS_SZ + boff);
        s = __builtin_amdgcn_mfma_f32_16x16x32_bf16(aqh[ks], bh, s, 0, 0, 0);
        s = __builtin_amdgcn_mfma_f32_16x16x32_bf16(aqh[ks], bl, s, 0, 0, 0);
        s = __builtin_amdgcn_mfma_f32_16x16x32_bf16(aql[ks], bh, s, 0, 0, 0);
      }
      S[e][j] = s;
    }

  // ---- Phase B: mask + softmax (C layout: row=lq*4+rr, col=lm) ----
  const float NEG = -3.0e38f;
  float mx[4] = {NEG, NEG, NEG, NEG};
#pragma unroll
  for (int e = 0; e < 4; ++e)
#pragma unroll
    for (int j = 0; j < 3; ++j) {
      const int sl = j * 16 + lm;
#pragma unroll
      for (int rr = 0; rr < 4; ++rr) {
        const int m = lq * 4 + rr;
        const bool valid = ((unsigned)(sl - m) <= 31u);
        const float v = valid ? S[e][j][rr] * 0.125f : NEG;
        S[e][j][rr] = v;
        mx[rr] = fmaxf(mx[rr], v);
      }
    }
#pragma unroll
  for (int rr = 0; rr < 4; ++rr) {
    float m = mx[rr];
    m = fmaxf(m, __shfl_xor(m, 1));
    m = fmaxf(m, __shfl_xor(m, 2));
    m = fmaxf(m, __shfl_xor(m, 4));
    m = fmaxf(m, __shfl_xor(m, 8));
    mx[rr] = m;
  }
  float sm[4] = {0.f, 0.f, 0.f, 0.f};
#pragma unroll
  for (int e = 0; e < 4; ++e)
#pragma unroll
    for (int j = 0; j < 3; ++j)
#pragma unroll
      for (int rr = 0; rr < 4; ++rr) {
        const float p = __expf(S[e][j][rr] - mx[rr]);
        S[e][j][rr] = p;
        sm[rr] += p;
      }
  float inv[4];
#pragma unroll
  for (int rr = 0; rr < 4; ++rr) {
    float s = sm[rr];
    s += __shfl_xor(s, 1);
    s += __shfl_xor(s, 2);
    s += __shfl_xor(s, 4);
    s += __shfl_xor(s, 8);
    inv[rr] = 1.0f / s;
  }

  // ---- Phase C: PV (no barriers; P is per-wave, Vt read-only) ----
  f32x4 O[4] = {};
#pragma unroll
  for (int e = 0; e < 4; ++e) {
#pragma unroll
    for (int j = 0; j < 3; ++j)
#pragma unroll
      for (int rr = 0; rr < 4; ++rr) {
        const float p = S[e][j][rr] * inv[rr];
        const unsigned short h = f2bf(p);
        lds[PWH + (lq * 4 + rr) * 72 + j * 16 + lm] = h;
        lds[PWL + (lq * 4 + rr) * 72 + j * 16 + lm] = f2bf(p - bf2f(h));
      }
    bf16x8 ah[2], al[2];
#pragma unroll
    for (int ks = 0; ks < 2; ++ks) {
      ah[ks] = *(const bf16x8*)(lds + PWH + lm * 72 + ks * 32 + lq * 8);
      al[ks] = *(const bf16x8*)(lds + PWL + lm * 72 + ks * 32 + lq * 8);
    }
#pragma unroll
    for (int nt = 0; nt < 4; ++nt)
#pragma unroll
      for (int ks = 0; ks < 2; ++ks) {
        const int boff = (nt * 16 + lm) * 80 + ks * 32 + lq * 8;
        bf16x8 vh = *(const bf16x8*)(lds + VT_B + e * VT_SZ + boff);
        O[nt] = __builtin_amdgcn_mfma_f32_16x16x32_bf16(ah[ks], vh, O[nt], 0, 0, 0);
        O[nt] = __builtin_amdgcn_mfma_f32_16x16x32_bf16(al[ks], vh, O[nt], 0, 0, 0);
      }
  }

#pragma unroll
  for (int nt = 0; nt < 4; ++nt)
#pragma unroll
    for (int rr = 0; rr < 4; ++rr) {
      const int t = t0 + lq * 4 + rr;
      const size_t oi = ((size_t)(n * 2048 + t)) * 512 + w * 64 + nt * 16 + lm;
      const float v = O[nt][rr];
      const unsigned short h = f2bf(v);
      Ybh[oi] = h;
      Ybl[oi] = f2bf(v - bf2f(h));
    }
}

// ---------------- K4: output GEMM (split-bf16 MFMA, BK=64) ----------------
__global__ __launch_bounds__(256) void gemm_out(
    const unsigned short* __restrict__ Yh, const unsigned short* __restrict__ Yl,
    const unsigned short* __restrict__ Wh, const unsigned short* __restrict__ Wl,
    float* __restrict__ out)
{
  __shared__ __align__(16) unsigned short Ash[2 * 128 * 32];
  __shared__ __align__(16) unsigned short Asl[2 * 128 * 32];
  __shared__ __align__(16) unsigned short Bsh[2 * 128 * 32];
  __shared__ __align__(16) unsigned short Bsl[2 * 128 * 32];
  const int tid  = threadIdx.x;
  const int lane = tid & 63;
  const int w    = tid >> 6;
  const int wr   = w >> 1, wc = w & 1;
  const int lm   = lane & 15, lq = lane >> 4;
  const int rb   = blockIdx.x * 128;
  const int cb   = blockIdx.y * 128;
  const int srow = lane >> 2;
  const int skc  = (lane & 3) * 8;

  f32x4 acc[4][4] = {};
  for (int k0 = 0; k0 < 512; k0 += 64) {
#pragma unroll
    for (int p = 0; p < 2; ++p)
#pragma unroll
      for (int c = 0; c < 2; ++c) {
        const int r0   = w * 32 + c * 16;
        const int ldso = (p * 128 + r0) * 32;
        const size_t ga = (size_t)(rb + r0 + srow) * 512 + k0 + p * 32 + skc;
        const size_t gb = (size_t)(cb + r0 + srow) * 512 + k0 + p * 32 + skc;
        GLDS(Yh + ga, Ash + ldso);
        GLDS(Yl + ga, Asl + ldso);
        GLDS(Wh + gb, Bsh + ldso);
        GLDS(Wl + gb, Bsl + ldso);
      }
    __syncthreads();
#pragma unroll
    for (int ks = 0; ks < 2; ++ks) {
      bf16x8 ah[4], al[4], bh[4], bl[4];
#pragma unroll
      for (int i = 0; i < 4; ++i) {
        const int off = (ks * 128 + wr * 64 + i * 16 + lm) * 32 + lq * 8;
        ah[i] = *(const bf16x8*)(Ash + off);
        al[i] = *(const bf16x8*)(Asl + off);
      }
#pragma unroll
      for (int j = 0; j < 4; ++j) {
        const int off = (ks * 128 + wc * 64 + j * 16 + lm) * 32 + lq * 8;
        bh[j] = *(const bf16x8*)(Bsh + off);
        bl[j] = *(const bf16x8*)(Bsl + off);
      }
#pragma unroll
      for (int i = 0; i < 4; ++i)
#pragma unroll
        for (int j = 0; j < 4; ++j) {
          acc[i][j] = __builtin_amdgcn_mfma_f32_16x16x32_bf16(ah[i], bh[j], acc[i][j], 0, 0, 0);
          acc[i][j] = __builtin_amdgcn_mfma_f32_16x16x32_bf16(ah[i], bl[j], acc[i][j], 0, 0, 0);
          acc[i][j] = __builtin_amdgcn_mfma_f32_16x16x32_bf16(al[i], bh[j], acc[i][j], 0, 0, 0);
        }
    }
    __syncthreads();
  }
#pragma unroll
  for (int i = 0; i < 4; ++i)
#pragma unroll
    for (int j = 0; j < 4; ++j)
#pragma unroll
      for (int rr = 0; rr < 4; ++rr) {
        const int m = rb + wr * 64 + i * 16 + lq * 4 + rr;
        const int c = cb + wc * 64 + j * 16 + lm;
        out[(size_t)m * 1024 + c] = acc[i][j][rr];
      }
}

extern "C" void kernel_launch(void* const* d_in, const int* in_sizes, int n_in,
                              void* d_out, int out_size, void* d_ws, size_t ws_size,
                              hipStream_t stream) {
  const float* X     = (const float*)d_in[0];
  const float* wG    = (const float*)d_in[1];
  const float* bG    = (const float*)d_in[2];
  const float* wK    = (const float*)d_in[3];
  const float* wV    = (const float*)d_in[4];
  const float* wQ    = (const float*)d_in[5];
  const float* wO    = (const float*)d_in[6];
  const float* initK = (const float*)d_in[7];
  const float* initV = (const float*)d_in[8];
  float* out = (float*)d_out;

  // --- workspace layout (51.4 MB, heavy lifetime aliasing) ---
  float* ws = (float*)d_ws;
  float* Kb = ws;                    // 2,097,152 f
  float* Vb = Kb + 2097152;          // 2,097,152 f
  float* Qb = Vb + 2097152;          // 2,097,152 f
  float* Gb = Qb + 2097152;          //   131,072 f
  unsigned short* Xh   = (unsigned short*)(Gb + 131072);  // 4,194,304 s
  unsigned short* Xl   = Xh + 4194304;                    // 4,194,304 s
  unsigned short* Wh   = Xl + 4194304;                    // 1,703,936 s
  unsigned short* Wl   = Wh + 1703936;                    // 1,703,936 s
  unsigned short* wOth = Wl + 1703936;                    //   524,288 s
  unsigned short* wOtl = wOth + 524288;                   //   524,288 s
  // aliases (lifetimes don't overlap):
  unsigned* P    = (unsigned*)Xh;       // X planes dead after gemm_proj
  unsigned* recK = P;                   // 1,064,960 u
  unsigned* recV = P + 1064960;         // 1,064,960 u
  unsigned* gK   = P + 2129920;         // 1,048,576 u
  unsigned* gV   = (unsigned*)Wh;       // 1,048,576 u (W planes dead after gemm_proj)
  float*   Afac  = (float*)(gV + 1048576);  // 16,384 f
  unsigned short* Ybh = (unsigned short*)Kb;  // Kb dead after gate_combine
  unsigned short* Ybl = Ybh + 2097152;

  cvt_XW<<<dim3(5760), dim3(256), 0, stream>>>(X, wK, wV, wQ, wG, Xh, Xl, Wh, Wl);
  cvt_wOt_split<<<dim3(32, 16), dim3(32, 8), 0, stream>>>(wO, wOth, wOtl);
  gemm_proj<<<dim3(32, 13), dim3(256), 0, stream>>>(Xh, Xl, Wh, Wl, bG, Kb, Vb, Qb, Gb);
  gate_combine<<<dim3(256), dim3(256), 0, stream>>>(Gb, Kb, Vb, Afac, gK, gV);
  scan2<<<dim3(8, 32, 2), dim3(64), 0, stream>>>(Afac, gK, gV, initK, initV, recK, recV);
  attn_kernel<<<dim3(256), dim3(512), 0, stream>>>(Qb, recK, recV, Ybh, Ybl);
  gemm_out<<<dim3(32, 8), dim3(256), 0, stream>>>(Ybh, Ybl, wOth, wOtl, out);
}

// Round 8
// 177.721 us; speedup vs baseline: 3.3619x; 1.0870x over previous
//
#include <hip/hip_runtime.h>
#include <math.h>

// Dims: N=2, T=2048, DM=1024, H=8, E=4, L=32, DK=DV=64
// Numerics: scan multiplier (1-sum_h G) ~ -1.4 => rec ~1e9, logits ~1e8
// (softmax==argmax). Pre-softmax paths (X,W,K,Q, rec_K) use split-bf16
// (hi+lo, ~2^-17): argmax-brittle. Post-softmax paths (P, V-use, Y, wO) are
// plain bf16: smooth ~2^-9 errors, ~3e6 on 1.77e9 output, under the 3.5e7
// threshold (verified R7: dropping V-lo left absmax at the 8.4e6 ULP floor).

typedef __attribute__((ext_vector_type(8))) short bf16x8;
typedef __attribute__((ext_vector_type(4))) float f32x4;

static __device__ __forceinline__ unsigned short f2bf(float f) {
  unsigned u = __float_as_uint(f);
  u += 0x7fffu + ((u >> 16) & 1u);   // RNE
  return (unsigned short)(u >> 16);
}
static __device__ __forceinline__ float bf2f(unsigned short h) {
  return __uint_as_float(((unsigned)h) << 16);
}
static __device__ __forceinline__ unsigned packbf(float f) {
  unsigned short h = f2bf(f);
  unsigned short l = f2bf(f - bf2f(h));
  return ((unsigned)h << 16) | (unsigned)l;
}
static __device__ __forceinline__ float unpackbf(unsigned u) {
  return __uint_as_float(u & 0xffff0000u) + __uint_as_float(u << 16);
}

#define GLDS(gp, lp) \
  __builtin_amdgcn_global_load_lds((const __attribute__((address_space(1))) void*)(gp), \
                                   (__attribute__((address_space(3))) void*)(lp), 16, 0, 0)

// ------- converts: X,W -> hi/lo planes; wO -> transposed hi plane (fused) ---
__global__ __launch_bounds__(256) void cvt_all(
    const float* __restrict__ X,
    const float* __restrict__ wK, const float* __restrict__ wV,
    const float* __restrict__ wQ, const float* __restrict__ wG,
    const float* __restrict__ wO,
    unsigned short* __restrict__ Xh, unsigned short* __restrict__ Xl,
    unsigned short* __restrict__ Wh, unsigned short* __restrict__ Wl,
    unsigned short* __restrict__ wOth)
{
  __shared__ float tile[32][33];
  const int b   = blockIdx.x;
  const int tid = threadIdx.x;
  if (b < 5760) {
    const int g = b * 256 + tid;
    const float* src;
    unsigned short *dh, *dl;
    int idx;
    if (g < 1048576) {              // X: 4,194,304 floats
      idx = g * 4;
      src = X + idx;
      dh = Xh + idx; dl = Xl + idx;
    } else {                        // W: 1664 rows x 1024
      idx = (g - 1048576) * 4;
      const int row = idx >> 10;
      const int col = idx & 1023;
      const float* s = nullptr;
      if (row < 512)       s = wK + (size_t)row * 1024;
      else if (row < 1024) s = wV + (size_t)(row - 512) * 1024;
      else if (row < 1536) s = wQ + (size_t)(row - 1024) * 1024;
      else if (row < 1568) s = wG + (size_t)(row - 1536) * 1024;
      src = s ? s + col : nullptr;
      dh = Wh + idx; dl = Wl + idx;
    }
    float4 v = make_float4(0.f, 0.f, 0.f, 0.f);
    if (src) v = *(const float4*)src;
    ushort4 h, l;
    h.x = f2bf(v.x); l.x = f2bf(v.x - bf2f(h.x));
    h.y = f2bf(v.y); l.y = f2bf(v.y - bf2f(h.y));
    h.z = f2bf(v.z); l.z = f2bf(v.z - bf2f(h.z));
    h.w = f2bf(v.w); l.w = f2bf(v.w - bf2f(h.w));
    *(ushort4*)dh = h;
    *(ushort4*)dl = l;
    return;
  }
  // wOt: wOth[n][k] = bf16(wO[k][n]); 512 blocks of 32x32 tiles
  const int b2 = b - 5760;
  const int n0 = (b2 & 31) * 32;
  const int k0 = (b2 >> 5) * 32;
  const int tx = tid & 31, ty = tid >> 5;
#pragma unroll
  for (int r = 0; r < 4; ++r)
    tile[ty * 4 + r][tx] = wO[(size_t)(k0 + ty * 4 + r) * 1024 + n0 + tx];
  __syncthreads();
#pragma unroll
  for (int r = 0; r < 4; ++r)
    wOth[(size_t)(n0 + ty * 4 + r) * 512 + k0 + tx] = f2bf(tile[tx][ty * 4 + r]);
}

// ---------------- K1: fused projection GEMM (split-bf16 MFMA, BK=64) --------
__global__ __launch_bounds__(256) void gemm_proj(
    const unsigned short* __restrict__ Xh, const unsigned short* __restrict__ Xl,
    const unsigned short* __restrict__ Wh, const unsigned short* __restrict__ Wl,
    const float* __restrict__ bG,
    float* __restrict__ Kb, float* __restrict__ Vb, float* __restrict__ Qb,
    float* __restrict__ Gb)
{
  __shared__ __align__(16) unsigned short Ash[2 * 128 * 32];
  __shared__ __align__(16) unsigned short Asl[2 * 128 * 32];
  __shared__ __align__(16) unsigned short Bsh[2 * 128 * 32];
  __shared__ __align__(16) unsigned short Bsl[2 * 128 * 32];
  const int tid  = threadIdx.x;
  const int lane = tid & 63;
  const int w    = tid >> 6;
  const int wr   = w >> 1, wc = w & 1;
  const int lm   = lane & 15, lq = lane >> 4;
  const int rb   = blockIdx.x * 128;
  const int cb   = blockIdx.y * 128;
  const int srow = lane >> 2;
  const int skc  = (lane & 3) * 8;

  f32x4 acc[4][4] = {};
  for (int k0 = 0; k0 < 1024; k0 += 64) {
#pragma unroll
    for (int p = 0; p < 2; ++p)
#pragma unroll
      for (int c = 0; c < 2; ++c) {
        const int r0   = w * 32 + c * 16;
        const int ldso = (p * 128 + r0) * 32;
        const size_t ga = (size_t)(rb + r0 + srow) * 1024 + k0 + p * 32 + skc;
        const size_t gb = (size_t)(cb + r0 + srow) * 1024 + k0 + p * 32 + skc;
        GLDS(Xh + ga, Ash + ldso);
        GLDS(Xl + ga, Asl + ldso);
        GLDS(Wh + gb, Bsh + ldso);
        GLDS(Wl + gb, Bsl + ldso);
      }
    __syncthreads();
#pragma unroll
    for (int ks = 0; ks < 2; ++ks) {
      bf16x8 ah[4], al[4], bh[4], bl[4];
#pragma unroll
      for (int i = 0; i < 4; ++i) {
        const int off = (ks * 128 + wr * 64 + i * 16 + lm) * 32 + lq * 8;
        ah[i] = *(const bf16x8*)(Ash + off);
        al[i] = *(const bf16x8*)(Asl + off);
      }
#pragma unroll
      for (int j = 0; j < 4; ++j) {
        const int off = (ks * 128 + wc * 64 + j * 16 + lm) * 32 + lq * 8;
        bh[j] = *(const bf16x8*)(Bsh + off);
        bl[j] = *(const bf16x8*)(Bsl + off);
      }
#pragma unroll
      for (int i = 0; i < 4; ++i)
#pragma unroll
        for (int j = 0; j < 4; ++j) {
          acc[i][j] = __builtin_amdgcn_mfma_f32_16x16x32_bf16(ah[i], bh[j], acc[i][j], 0, 0, 0);
          acc[i][j] = __builtin_amdgcn_mfma_f32_16x16x32_bf16(ah[i], bl[j], acc[i][j], 0, 0, 0);
          acc[i][j] = __builtin_amdgcn_mfma_f32_16x16x32_bf16(al[i], bh[j], acc[i][j], 0, 0, 0);
        }
    }
    __syncthreads();
  }
#pragma unroll
  for (int i = 0; i < 4; ++i) {
#pragma unroll
    for (int j = 0; j < 4; ++j) {
      const int c = cb + wc * 64 + j * 16 + lm;
      if (c >= 1568) continue;
#pragma unroll
      for (int rr = 0; rr < 4; ++rr) {
        const int m = rb + wr * 64 + i * 16 + lq * 4 + rr;
        const int n = m >> 11, t = m & 2047;
        const float v = acc[i][j][rr];
        if (c < 512) {
          Kb[(size_t)((n * 8 + (c >> 6)) * 2048 + t) * 64 + (c & 63)] = v;
        } else if (c < 1024) {
          const int cc = c - 512;
          Vb[(size_t)((n * 8 + (cc >> 6)) * 2048 + t) * 64 + (cc & 63)] = v;
        } else if (c < 1536) {
          const int cc = c - 1024;
          Qb[(size_t)((n * 8 + (cc >> 6)) * 2048 + t) * 64 + (cc & 63)] = v;
        } else {
          const int cc = c - 1536;  // h*4+e
          const float g = 1.0f / (1.0f + __expf(-(v + bG[cc])));
          Gb[(size_t)(n * 32 + cc) * 2048 + t] = g;
        }
      }
    }
  }
}

// ---------------- S1: gate + combine (e-inner; K/V read once) ----------------
__global__ __launch_bounds__(256) void gate_combine(
    const float* __restrict__ Gb,   // (n, h*4+e, t)
    const float* __restrict__ Kb,   // (n,h,t,d)
    const float* __restrict__ Vb,
    float* __restrict__ Afac,       // (n,e,t)
    unsigned* __restrict__ gK,      // (n,e,t,d) packed
    unsigned* __restrict__ gV)
{
  __shared__ float Gs[16][32];      // [tl][h*4+e]
  const int tid = threadIdx.x;
  const int n   = blockIdx.x >> 7;
  const int t0  = (blockIdx.x & 127) * 16;
  for (int idx = tid; idx < 512; idx += 256) {
    const int he = idx & 31, tl = idx >> 5;
    Gs[tl][he] = Gb[((size_t)n * 32 + he) * 2048 + t0 + tl];
  }
  __syncthreads();
  const int d  = tid & 63;
  const int ts = tid >> 6;          // 0..3
#pragma unroll
  for (int tt = 0; tt < 4; ++tt) {
    const int tl = ts * 4 + tt;
    const int t  = t0 + tl;
    float ak[4] = {}, av[4] = {};
#pragma unroll
    for (int h = 0; h < 8; ++h) {
      const float kk = Kb[(size_t)((n * 8 + h) * 2048 + t) * 64 + d];
      const float vv = Vb[(size_t)((n * 8 + h) * 2048 + t) * 64 + d];
#pragma unroll
      for (int e = 0; e < 4; ++e) {
        const float g = Gs[tl][h * 4 + e];
        ak[e] = fmaf(g, kk, ak[e]);
        av[e] = fmaf(g, vv, av[e]);
      }
    }
#pragma unroll
    for (int e = 0; e < 4; ++e) {
      const size_t o = (size_t)((n * 4 + e) * 2048 + t) * 64 + d;
      gK[o] = packbf(ak[e]);
      gV[o] = packbf(av[e]);
    }
  }
  if (tid < 64) {
    const int e = tid & 3, tl = tid >> 2;
    float gs = 0.f;
#pragma unroll
    for (int h = 0; h < 8; ++h) gs += Gs[tl][h * 4 + e];
    Afac[(size_t)(n * 4 + e) * 2048 + t0 + tl] = 1.0f - gs;
  }
}

// ---------------- S2: lag-32 linear scan (streaming, prefetched) -----------
__global__ __launch_bounds__(64) void scan2(
    const float* __restrict__ Afac,   // (n,e,t)
    const unsigned* __restrict__ gK,  // (n,e,t,d) packed
    const unsigned* __restrict__ gV,
    const float* __restrict__ initK,  // (E,32,64)
    const float* __restrict__ initV,
    unsigned* __restrict__ recK,      // (n,e,2080,64) packed
    unsigned* __restrict__ recV)
{
  const int d  = threadIdx.x;
  const int ne = blockIdx.x;
  const int i  = blockIdx.y;
  const int e  = ne & 3;
  const bool isV = (blockIdx.z != 0);
  const unsigned* src = (isV ? gV : gK) + ((size_t)ne * 2048 + i) * 64 + d;
  const float*   init = isV ? initV : initK;
  unsigned*       rec = isV ? recV : recK;

  float y = init[(size_t)(e * 32 + i) * 64 + d];
  rec[(size_t)(ne * 2080 + i) * 64 + d] = packbf(y);
  const float* Arow = Afac + (size_t)ne * 2048 + i;
  unsigned* dst = rec + ((size_t)ne * 2080 + 32 + i) * 64 + d;

  unsigned u0[8];
  float    a0[8];
#pragma unroll
  for (int k = 0; k < 8; ++k) {
    a0[k] = Arow[k * 32];
    u0[k] = src[(size_t)k * 2048];
  }
  for (int J = 0; J < 64; J += 8) {
    unsigned u1[8];
    float    a1[8];
    if (J + 8 < 64) {
#pragma unroll
      for (int k = 0; k < 8; ++k) {
        a1[k] = Arow[(J + 8 + k) * 32];
        u1[k] = src[(size_t)(J + 8 + k) * 2048];
      }
    }
#pragma unroll
    for (int k = 0; k < 8; ++k) {
      y = fmaf(a0[k], y, unpackbf(u0[k]));
      dst[(size_t)(J + k) * 2048] = packbf(y);
    }
#pragma unroll
    for (int k = 0; k < 8; ++k) { a0[k] = a1[k]; u0[k] = u1[k]; }
  }
}

// ---------------- K3: banded MFMA attention (single-barrier) ----------------
// Block: (n, 16 t-rows), 512 thr = 8 waves (wave=head).
// LDS (shorts): Ks hi/lo 4e x [48 s][72], Vt hi 4e x [64 d][80] (cols 48..63
// zeroed, 64..79 never read), per-wave P hi [16][72] (cols 48..63 zeroed).
// Total 57,344 shorts = 114,688 B. In-bounds: Ks max 3447<3456,
// Vt max 5103<5120, P max 1143<1152.
#define TB 16
#define KS_SZ 3456            // 48*72 per e per plane
#define KS_LO 13824           // 4*KS_SZ
#define VT_B  27648
#define VT_SZ 5120            // 64*80 per e (hi only)
#define P_B   48128           // VT_B + 4*VT_SZ
__global__ __launch_bounds__(512) void attn_kernel(
    const float* __restrict__ Qb,       // (n,h,t,64) f32
    const unsigned* __restrict__ recK,  // (n,e,2080,64) packed
    const unsigned* __restrict__ recV,
    unsigned short* __restrict__ Ybh)   // (n*T,512) bf16
{
  __shared__ __align__(16) unsigned short lds[57344];
  const int tid  = threadIdx.x;
  const int lane = tid & 63;
  const int w    = tid >> 6;           // head
  const int lm   = lane & 15, lq = lane >> 4;
  const int n    = blockIdx.x >> 7;
  const int t0   = (blockIdx.x & 127) * TB;
  const int maxidx = (2078 - t0) * 64 + 63;   // clamp reads to s<=2079

  // Q A-frags (hi/lo x 2 ksteps) straight from global
  bf16x8 aqh[2], aql[2];
  {
    const float* qrow = Qb + ((size_t)(n * 8 + w) * 2048 + t0 + lm) * 64 + lq * 8;
#pragma unroll
    for (int ks = 0; ks < 2; ++ks) {
      float4 q0 = *(const float4*)(qrow + ks * 32);
      float4 q1 = *(const float4*)(qrow + ks * 32 + 4);
      float qv[8] = {q0.x, q0.y, q0.z, q0.w, q1.x, q1.y, q1.z, q1.w};
#pragma unroll
      for (int j = 0; j < 8; ++j) {
        unsigned short h = f2bf(qv[j]);
        aqh[ks][j] = (short)h;
        aql[ks][j] = (short)f2bf(qv[j] - bf2f(h));
      }
    }
  }

  // ---- stage K hi/lo + V^T hi for all 4 experts ----
#pragma unroll
  for (int e = 0; e < 4; ++e) {
    const unsigned* sK = recK + ((size_t)(n * 4 + e) * 2080 + t0 + 1) * 64;
    const unsigned* sV = recV + ((size_t)(n * 4 + e) * 2080 + t0 + 1) * 64;
#pragma unroll
    for (int p = 0; p < 6; ++p) {
      const int idx = tid + p * 512;
      const int ci  = idx <= maxidx ? idx : maxidx;
      const int sl  = idx >> 6, d = idx & 63;
      const unsigned uk = sK[ci];
      const unsigned uv = sV[ci];
      lds[e * KS_SZ + sl * 72 + d]         = (unsigned short)(uk >> 16);
      lds[KS_LO + e * KS_SZ + sl * 72 + d] = (unsigned short)(uk & 0xffffu);
      lds[VT_B + e * VT_SZ + d * 80 + sl]  = (unsigned short)(uv >> 16);
    }
  }
  // zero Vt pad cols 48..63 (read by PV kstep1 with P=0 there; must be finite)
  for (int idx = tid; idx < 2048; idx += 512) {   // dword writes
    const int e = idx >> 9, r = idx & 511;
    const int d = r >> 3, c = r & 7;
    *(unsigned*)(lds + VT_B + e * VT_SZ + d * 80 + 48 + c * 2) = 0u;
  }
  // zero this wave's P pad cols 48..63 (own region, no barrier needed)
  const int PWH = P_B + w * 1152;
  {
    const int r = lane >> 2, c0 = 48 + (lane & 3) * 4;
#pragma unroll
    for (int c = 0; c < 4; ++c) lds[PWH + r * 72 + c0 + c] = 0;
  }
  __syncthreads();   // the ONLY block barrier

  // ---- Phase A: scores (split-bf16, 3-term: logits need argmax fidelity) ---
  f32x4 S[4][3];
#pragma unroll
  for (int e = 0; e < 4; ++e)
#pragma unroll
    for (int j = 0; j < 3; ++j) {
      f32x4 s = {0.f, 0.f, 0.f, 0.f};
#pragma unroll
      for (int ks = 0; ks < 2; ++ks) {
        const int boff = (j * 16 + lm) * 72 + ks * 32 + lq * 8;
        bf16x8 bh = *(const bf16x8*)(lds + e * KS_SZ + boff);
        bf16x8 bl = *(const bf16x8*)(lds + KS_LO + e * KS_SZ + boff);
        s = __builtin_amdgcn_mfma_f32_16x16x32_bf16(aqh[ks], bh, s, 0, 0, 0);
        s = __builtin_amdgcn_mfma_f32_16x16x32_bf16(aqh[ks], bl, s, 0, 0, 0);
        s = __builtin_amdgcn_mfma_f32_16x16x32_bf16(aql[ks], bh, s, 0, 0, 0);
      }
      S[e][j] = s;
    }

  // ---- Phase B: mask + softmax (C layout: row=lq*4+rr, col=lm) ----
  const float NEG = -3.0e38f;
  float mx[4] = {NEG, NEG, NEG, NEG};
#pragma unroll
  for (int e = 0; e < 4; ++e)
#pragma unroll
    for (int j = 0; j < 3; ++j) {
      const int sl = j * 16 + lm;
#pragma unroll
      for (int rr = 0; rr < 4; ++rr) {
        const int m = lq * 4 + rr;
        const bool valid = ((unsigned)(sl - m) <= 31u);
        const float v = valid ? S[e][j][rr] * 0.125f : NEG;
        S[e][j][rr] = v;
        mx[rr] = fmaxf(mx[rr], v);
      }
    }
#pragma unroll
  for (int rr = 0; rr < 4; ++rr) {
    float m = mx[rr];
    m = fmaxf(m, __shfl_xor(m, 1));
    m = fmaxf(m, __shfl_xor(m, 2));
    m = fmaxf(m, __shfl_xor(m, 4));
    m = fmaxf(m, __shfl_xor(m, 8));
    mx[rr] = m;
  }
  float sm[4] = {0.f, 0.f, 0.f, 0.f};
#pragma unroll
  for (int e = 0; e < 4; ++e)
#pragma unroll
    for (int j = 0; j < 3; ++j)
#pragma unroll
      for (int rr = 0; rr < 4; ++rr) {
        const float p = __expf(S[e][j][rr] - mx[rr]);
        S[e][j][rr] = p;
        sm[rr] += p;
      }
  float inv[4];
#pragma unroll
  for (int rr = 0; rr < 4; ++rr) {
    float s = sm[rr];
    s += __shfl_xor(s, 1);
    s += __shfl_xor(s, 2);
    s += __shfl_xor(s, 4);
    s += __shfl_xor(s, 8);
    inv[rr] = 1.0f / s;
  }

  // ---- Phase C: PV, plain bf16 P (post-softmax; no barriers) ----
  f32x4 O[4] = {};
#pragma unroll
  for (int e = 0; e < 4; ++e) {
#pragma unroll
    for (int j = 0; j < 3; ++j)
#pragma unroll
      for (int rr = 0; rr < 4; ++rr)
        lds[PWH + (lq * 4 + rr) * 72 + j * 16 + lm] = f2bf(S[e][j][rr] * inv[rr]);
    bf16x8 ah[2];
#pragma unroll
    for (int ks = 0; ks < 2; ++ks)
      ah[ks] = *(const bf16x8*)(lds + PWH + lm * 72 + ks * 32 + lq * 8);
#pragma unroll
    for (int nt = 0; nt < 4; ++nt)
#pragma unroll
      for (int ks = 0; ks < 2; ++ks) {
        const int boff = (nt * 16 + lm) * 80 + ks * 32 + lq * 8;
        bf16x8 vh = *(const bf16x8*)(lds + VT_B + e * VT_SZ + boff);
        O[nt] = __builtin_amdgcn_mfma_f32_16x16x32_bf16(ah[ks], vh, O[nt], 0, 0, 0);
      }
  }

#pragma unroll
  for (int nt = 0; nt < 4; ++nt)
#pragma unroll
    for (int rr = 0; rr < 4; ++rr) {
      const int t = t0 + lq * 4 + rr;
      const size_t oi = ((size_t)(n * 2048 + t)) * 512 + w * 64 + nt * 16 + lm;
      Ybh[oi] = f2bf(O[nt][rr]);
    }
}

// ---------------- K4: output GEMM (plain bf16 MFMA, BK=64) ----------------
// out[r][c] = sum_k Y[r][k]*wOt[c][k]; M=4096, N=1024, K=512
__global__ __launch_bounds__(256) void gemm_out(
    const unsigned short* __restrict__ Yh,
    const unsigned short* __restrict__ Wh,
    float* __restrict__ out)
{
  __shared__ __align__(16) unsigned short Ash[2 * 128 * 32];
  __shared__ __align__(16) unsigned short Bsh[2 * 128 * 32];
  const int tid  = threadIdx.x;
  const int lane = tid & 63;
  const int w    = tid >> 6;
  const int wr   = w >> 1, wc = w & 1;
  const int lm   = lane & 15, lq = lane >> 4;
  const int rb   = blockIdx.x * 128;
  const int cb   = blockIdx.y * 128;
  const int srow = lane >> 2;
  const int skc  = (lane & 3) * 8;

  f32x4 acc[4][4] = {};
  for (int k0 = 0; k0 < 512; k0 += 64) {
#pragma unroll
    for (int p = 0; p < 2; ++p)
#pragma unroll
      for (int c = 0; c < 2; ++c) {
        const int r0   = w * 32 + c * 16;
        const int ldso = (p * 128 + r0) * 32;
        GLDS(Yh + (size_t)(rb + r0 + srow) * 512 + k0 + p * 32 + skc, Ash + ldso);
        GLDS(Wh + (size_t)(cb + r0 + srow) * 512 + k0 + p * 32 + skc, Bsh + ldso);
      }
    __syncthreads();
#pragma unroll
    for (int ks = 0; ks < 2; ++ks) {
      bf16x8 ah[4], bh[4];
#pragma unroll
      for (int i = 0; i < 4; ++i)
        ah[i] = *(const bf16x8*)(Ash + (ks * 128 + wr * 64 + i * 16 + lm) * 32 + lq * 8);
#pragma unroll
      for (int j = 0; j < 4; ++j)
        bh[j] = *(const bf16x8*)(Bsh + (ks * 128 + wc * 64 + j * 16 + lm) * 32 + lq * 8);
#pragma unroll
      for (int i = 0; i < 4; ++i)
#pragma unroll
        for (int j = 0; j < 4; ++j)
          acc[i][j] = __builtin_amdgcn_mfma_f32_16x16x32_bf16(ah[i], bh[j], acc[i][j], 0, 0, 0);
    }
    __syncthreads();
  }
#pragma unroll
  for (int i = 0; i < 4; ++i)
#pragma unroll
    for (int j = 0; j < 4; ++j)
#pragma unroll
      for (int rr = 0; rr < 4; ++rr) {
        const int m = rb + wr * 64 + i * 16 + lq * 4 + rr;
        const int c = cb + wc * 64 + j * 16 + lm;
        out[(size_t)m * 1024 + c] = acc[i][j][rr];
      }
}

extern "C" void kernel_launch(void* const* d_in, const int* in_sizes, int n_in,
                              void* d_out, int out_size, void* d_ws, size_t ws_size,
                              hipStream_t stream) {
  const float* X     = (const float*)d_in[0];
  const float* wG    = (const float*)d_in[1];
  const float* bG    = (const float*)d_in[2];
  const float* wK    = (const float*)d_in[3];
  const float* wV    = (const float*)d_in[4];
  const float* wQ    = (const float*)d_in[5];
  const float* wO    = (const float*)d_in[6];
  const float* initK = (const float*)d_in[7];
  const float* initV = (const float*)d_in[8];
  float* out = (float*)d_out;

  // --- workspace layout (heavy lifetime aliasing) ---
  float* ws = (float*)d_ws;
  float* Kb = ws;                    // 2,097,152 f
  float* Vb = Kb + 2097152;          // 2,097,152 f
  float* Qb = Vb + 2097152;          // 2,097,152 f
  float* Gb = Qb + 2097152;          //   131,072 f
  unsigned short* Xh   = (unsigned short*)(Gb + 131072);  // 4,194,304 s
  unsigned short* Xl   = Xh + 4194304;                    // 4,194,304 s
  unsigned short* Wh   = Xl + 4194304;                    // 1,703,936 s
  unsigned short* Wl   = Wh + 1703936;                    // 1,703,936 s
  unsigned short* wOth = Wl + 1703936;                    //   524,288 s
  // aliases (lifetimes don't overlap):
  unsigned* P    = (unsigned*)Xh;       // X planes dead after gemm_proj
  unsigned* recK = P;                   // 1,064,960 u
  unsigned* recV = P + 1064960;         // 1,064,960 u
  unsigned* gK   = P + 2129920;         // 1,048,576 u
  unsigned* gV   = (unsigned*)Wh;       // 1,048,576 u (W planes dead after gemm_proj)
  float*   Afac  = (float*)(gV + 1048576);  // 16,384 f (inside Wh+Wl region)
  unsigned short* Ybh = (unsigned short*)Kb;  // Kb dead after gate_combine

  cvt_all<<<dim3(6272), dim3(256), 0, stream>>>(X, wK, wV, wQ, wG, wO,
                                                Xh, Xl, Wh, Wl, wOth);
  gemm_proj<<<dim3(32, 13), dim3(256), 0, stream>>>(Xh, Xl, Wh, Wl, bG, Kb, Vb, Qb, Gb);
  gate_combine<<<dim3(256), dim3(256), 0, stream>>>(Gb, Kb, Vb, Afac, gK, gV);
  scan2<<<dim3(8, 32, 2), dim3(64), 0, stream>>>(Afac, gK, gV, initK, initV, recK, recV);
  attn_kernel<<<dim3(256), dim3(512), 0, stream>>>(Qb, recK, recV, Ybh);
  gemm_out<<<dim3(32, 8), dim3(256), 0, stream>>>(Ybh, wOth, out);
}